// Round 2
// baseline (1869.778 us; speedup 1.0000x reference)
//
#include <hip/hip_runtime.h>

#define NN 50000
#define EE 800000
#define HD 256

typedef __bf16 bf16;
typedef bf16 bf16x8 __attribute__((ext_vector_type(8)));
typedef bf16 bf16x4 __attribute__((ext_vector_type(4)));
typedef float f32x4 __attribute__((ext_vector_type(4)));

__device__ __forceinline__ float silu_f(float v) { return v / (1.f + __expf(-v)); }

// packed-weight linear index -> (k, col). Layout: [kc][nc][lane][r], r=0..7
__device__ __forceinline__ void pk_idx(int p, int& k, int& col) {
  int r = p & 7;
  int lane = (p >> 3) & 63;
  int nc = (p >> 9) & 15;
  int kc = p >> 13;
  k = kc * 32 + ((lane >> 4) << 3) + r;
  col = (nc << 4) + (lane & 15);
}

// bf16x2 packed atomic add (device scope). addr must be 4B-aligned.
__device__ __forceinline__ void atomic_pk_add_bf16(bf16* addr, float a, float b) {
  union { bf16 h[2]; unsigned int u; } p;
  p.h[0] = (bf16)a; p.h[1] = (bf16)b;
  asm volatile("global_atomic_pk_add_bf16 %0, %1, off"
               :: "v"((unsigned long long)(uintptr_t)addr), "v"(p.u) : "memory");
}

// ---------------- prep: zero m_i (bf16), copy x->xout, pack weights ----------------
__global__ __launch_bounds__(256) void prep_kernel(
    const float* __restrict__ x,
    const float* __restrict__ We1, const float* __restrict__ We2,
    const float* __restrict__ Wc1, const float* __restrict__ Wn1,
    const float* __restrict__ Wn2,
    bf16* __restrict__ m_i, float* __restrict__ xout,
    bf16* __restrict__ We1p, bf16* __restrict__ We2p, bf16* __restrict__ Wc1p,
    bf16* __restrict__ Wn1p, bf16* __restrict__ Wn2p)
{
  const int stride = gridDim.x * blockDim.x;
  for (int i = blockIdx.x * blockDim.x + threadIdx.x; i < NN * HD / 2; i += stride) {
    ((unsigned int*)m_i)[i] = 0u;  // zero 2 bf16 per thread
    if (i < 3 * NN) xout[i] = x[i];
    if (i < 19 * 8192) {  // We1 packed: K-order = h_src(256) h_dst(256) ea(64) dsq(1) zeros(31)
      int k, col; pk_idx(i, k, col);
      float v = 0.f;
      if (k < 512) v = We1[k * HD + col];
      else if (k < 576) v = We1[(k + 1) * HD + col];  // edge_attr rows 513..576
      else if (k == 576) v = We1[512 * HD + col];     // dist_sq row
      We1p[i] = (bf16)v;
    }
    if (i < 8 * 8192) {
      int k, col; pk_idx(i, k, col);
      We2p[i] = (bf16)We2[k * HD + col];
      Wc1p[i] = (bf16)Wc1[k * HD + col];
      Wn2p[i] = (bf16)Wn2[k * HD + col];
    }
    if (i < 16 * 8192) {
      int k, col; pk_idx(i, k, col);
      Wn1p[i] = (bf16)Wn1[k * HD + col];
    }
  }
}

__device__ __forceinline__ void zero_acc(f32x4 acc[2][4]) {
#pragma unroll
  for (int m = 0; m < 2; ++m)
#pragma unroll
    for (int t = 0; t < 4; ++t)
#pragma unroll
      for (int r = 0; r < 4; ++r) acc[m][t][r] = 0.f;
}

// 32 rows (2 M-tiles) x 64 cols (4 N-tiles per wave) GEMM step.
// A layout: row = lane&15, k = (lane>>4)*8 + r  (LDS, pitch = odd*16B)
// B layout: packed [kc][nc][lane][8] -> one 16B load per fragment
template <int KC>
__device__ __forceinline__ void mm_layer(const bf16* __restrict__ Asrc, int pitch,
                                         const bf16* __restrict__ Wp, int lane, int nc0,
                                         f32x4 acc[2][4])
{
  const int la = lane & 15, lb = lane >> 4;
#pragma unroll 2
  for (int kc = 0; kc < KC; ++kc) {
    bf16x8 a0 = *(const bf16x8*)&Asrc[la * pitch + kc * 32 + lb * 8];
    bf16x8 a1 = *(const bf16x8*)&Asrc[(16 + la) * pitch + kc * 32 + lb * 8];
    const bf16x8* wp = (const bf16x8*)Wp + ((kc * 16 + nc0) * 64 + lane);
#pragma unroll
    for (int t = 0; t < 4; ++t) {
      bf16x8 b = wp[t * 64];
      acc[0][t] = __builtin_amdgcn_mfma_f32_16x16x32_bf16(a0, b, acc[0][t], 0, 0, 0);
      acc[1][t] = __builtin_amdgcn_mfma_f32_16x16x32_bf16(a1, b, acc[1][t], 0, 0, 0);
    }
  }
}

constexpr int EB = 64;      // edges per block
constexpr int EIN_P = 616;  // 608 used + pad -> 1232B = 77*16B (odd) : conflict-free b128
constexpr int T1_P = 264;   // 528B = 33*16B (odd)

// ---------------- edge kernel: 3 fused GEMM layers + scatters --------------------
// 512 threads = 8 waves: wave (wv>>2) owns 32-row half, (wv&3) owns 64-col quarter.
// t1s/mjs live inside the ein buffer (disjoint lifetimes, barrier-separated).
__global__ __launch_bounds__(512, 4) void edge_kernel(
    const float* __restrict__ h, const float* __restrict__ x,
    const int* __restrict__ ei, const float* __restrict__ ea,
    const bf16* __restrict__ We1p, const float* __restrict__ be1,
    const bf16* __restrict__ We2p, const float* __restrict__ be2,
    const bf16* __restrict__ Wc1p, const float* __restrict__ bc1,
    const float* __restrict__ Wc2,
    bf16* __restrict__ m_i, float* __restrict__ xout)
{
  __shared__ __align__(16) bf16 ein[EB * EIN_P];  // 78,848 B; t1s/mjs alias this
  __shared__ float rel0[EB], rel1[EB], rel2[EB];
  __shared__ float cw[EB];
  __shared__ int sidx[EB], didx[EB];
  bf16* const t1s = ein;  // layer-1 output (and later m_ij), EB x T1_P

  const int tid = threadIdx.x;
  const int e0 = blockIdx.x * EB;

  if (tid < EB) {
    int e = e0 + tid;
    int s = ei[e], d = ei[EE + e];
    sidx[tid] = s; didx[tid] = d;
    float rx = x[3 * s + 0] - x[3 * d + 0];
    float ry = x[3 * s + 1] - x[3 * d + 1];
    float rz = x[3 * s + 2] - x[3 * d + 2];
    rel0[tid] = rx; rel1[tid] = ry; rel2[tid] = rz;
    cw[tid] = 0.f;
  }
  __syncthreads();

  // gather h[src] | h[dst] | edge_attr | dsq -> bf16 LDS (coalesced: 1 row per wave pass)
  for (int i = tid; i < EB * 64; i += 512) {
    int er = i >> 6, q = i & 63;
    float4 v = ((const float4*)h)[(long)sidx[er] * 64 + q];
    bf16x4 b; b[0] = (bf16)v.x; b[1] = (bf16)v.y; b[2] = (bf16)v.z; b[3] = (bf16)v.w;
    *(bf16x4*)&ein[er * EIN_P + q * 4] = b;
  }
  for (int i = tid; i < EB * 64; i += 512) {
    int er = i >> 6, q = i & 63;
    float4 v = ((const float4*)h)[(long)didx[er] * 64 + q];
    bf16x4 b; b[0] = (bf16)v.x; b[1] = (bf16)v.y; b[2] = (bf16)v.z; b[3] = (bf16)v.w;
    *(bf16x4*)&ein[er * EIN_P + 256 + q * 4] = b;
  }
  for (int i = tid; i < EB * 16; i += 512) {
    int er = i >> 4, q = i & 15;
    float4 v = ((const float4*)ea)[(long)(e0 + er) * 16 + q];
    bf16x4 b; b[0] = (bf16)v.x; b[1] = (bf16)v.y; b[2] = (bf16)v.z; b[3] = (bf16)v.w;
    *(bf16x4*)&ein[er * EIN_P + 512 + q * 4] = b;
  }
  if (tid < EB) {
    float dsq = rel0[tid] * rel0[tid] + rel1[tid] * rel1[tid] + rel2[tid] * rel2[tid];
    ein[tid * EIN_P + 576] = (bf16)dsq;
    for (int k2 = 577; k2 < 608; ++k2) ein[tid * EIN_P + k2] = (bf16)0.f;
  }
  __syncthreads();

  const int lane = tid & 63;
  const int wv = tid >> 6;
  const int la = lane & 15, lb = lane >> 4;
  const int rbase = (wv >> 2) * 32;   // row half
  const int nc0 = (wv & 3) * 4;       // col quarter

  f32x4 acc[2][4];

  // ---- layer 1 ----
  zero_acc(acc);
  mm_layer<19>(ein + rbase * EIN_P, EIN_P, We1p, lane, nc0, acc);
  __syncthreads();  // all waves done READING ein before t1s overwrites it
#pragma unroll
  for (int t = 0; t < 4; ++t) {
    int col = (nc0 + t) * 16 + la;
    float bias = be1[col];
#pragma unroll
    for (int m = 0; m < 2; ++m)
#pragma unroll
      for (int r = 0; r < 4; ++r) {
        int row = rbase + m * 16 + lb * 4 + r;
        t1s[row * T1_P + col] = (bf16)silu_f(acc[m][t][r] + bias);
      }
  }
  __syncthreads();

  // ---- layer 2 (m_ij) ----
  zero_acc(acc);
  mm_layer<8>(t1s + rbase * T1_P, T1_P, We2p, lane, nc0, acc);
  int dr[2][4];
#pragma unroll
  for (int m = 0; m < 2; ++m)
#pragma unroll
    for (int r = 0; r < 4; ++r) dr[m][r] = didx[rbase + m * 16 + lb * 4 + r];
  __syncthreads();  // all waves done reading t1s before mjs overwrites it
#pragma unroll
  for (int t = 0; t < 4; ++t) {
    int col = (nc0 + t) * 16 + la;
    float bias = be2[col];
#pragma unroll
    for (int m = 0; m < 2; ++m)
#pragma unroll
      for (int r = 0; r < 4; ++r) {
        int row = rbase + m * 16 + lb * 4 + r;
        float mv = silu_f(acc[m][t][r] + bias);
        t1s[row * T1_P + col] = (bf16)mv;  // mjs overlays t1s
        float mo = __shfl_xor(mv, 1);      // partner column value
        if ((la & 1) == 0)
          atomic_pk_add_bf16(&m_i[(long)dr[m][r] * HD + col], mv, mo);
      }
  }
  __syncthreads();

  // ---- layer 3 (coord weight) ----
  zero_acc(acc);
  mm_layer<8>(t1s + rbase * T1_P, T1_P, Wc1p, lane, nc0, acc);
  float pr[2][4];
#pragma unroll
  for (int m = 0; m < 2; ++m)
#pragma unroll
    for (int r = 0; r < 4; ++r) pr[m][r] = 0.f;
#pragma unroll
  for (int t = 0; t < 4; ++t) {
    int col = (nc0 + t) * 16 + la;
    float bias = bc1[col];
    float wc = Wc2[col];
#pragma unroll
    for (int m = 0; m < 2; ++m)
#pragma unroll
      for (int r = 0; r < 4; ++r)
        pr[m][r] += silu_f(acc[m][t][r] + bias) * wc;
  }
#pragma unroll
  for (int m = 0; m < 2; ++m)
#pragma unroll
    for (int r = 0; r < 4; ++r) {
      float v = pr[m][r];
      v += __shfl_xor(v, 1);
      v += __shfl_xor(v, 2);
      v += __shfl_xor(v, 4);
      v += __shfl_xor(v, 8);
      if (la == 0) atomicAdd(&cw[rbase + m * 16 + lb * 4 + r], v);
    }
  __syncthreads();

  if (tid < EB) {
    float wgt = cw[tid];
    int d = didx[tid];
    atomicAdd(&xout[3 * d + 0], rel0[tid] * wgt);
    atomicAdd(&xout[3 * d + 1], rel1[tid] * wgt);
    atomicAdd(&xout[3 * d + 2], rel2[tid] * wgt);
  }
}

constexpr int NB = 64;
constexpr int NIN_P = 520;  // 1040B = 65*16B (odd)

// ---------------- node kernel: h_out = h + node_mlp([h, m_i]) --------------------
__global__ __launch_bounds__(512, 4) void node_kernel(
    const float* __restrict__ h, const bf16* __restrict__ m_i,
    const bf16* __restrict__ Wn1p, const float* __restrict__ bn1,
    const bf16* __restrict__ Wn2p, const float* __restrict__ bn2,
    float* __restrict__ hout)
{
  __shared__ __align__(16) bf16 nin[NB * NIN_P];  // 66,560 B; tls aliases this
  bf16* const tls = nin;
  const int tid = threadIdx.x;
  const long n0 = (long)blockIdx.x * NB;

  for (int i = tid; i < NB * 64; i += 512) {
    int nr = i >> 6, q = i & 63;
    long row = n0 + nr; if (row >= NN) row = NN - 1;
    float4 v = ((const float4*)h)[row * 64 + q];
    bf16x4 b; b[0] = (bf16)v.x; b[1] = (bf16)v.y; b[2] = (bf16)v.z; b[3] = (bf16)v.w;
    *(bf16x4*)&nin[nr * NIN_P + q * 4] = b;
  }
  for (int i = tid; i < NB * 32; i += 512) {
    int nr = i >> 5, q = i & 31;
    long row = n0 + nr; if (row >= NN) row = NN - 1;
    *(bf16x8*)&nin[nr * NIN_P + 256 + q * 8] = *(const bf16x8*)&m_i[row * HD + q * 8];
  }
  __syncthreads();

  const int lane = tid & 63;
  const int wv = tid >> 6;
  const int la = lane & 15, lb = lane >> 4;
  const int rbase = (wv >> 2) * 32;
  const int nc0 = (wv & 3) * 4;

  f32x4 acc[2][4];
  zero_acc(acc);
  mm_layer<16>(nin + rbase * NIN_P, NIN_P, Wn1p, lane, nc0, acc);
  __syncthreads();  // done reading nin
#pragma unroll
  for (int t = 0; t < 4; ++t) {
    int col = (nc0 + t) * 16 + la;
    float bias = bn1[col];
#pragma unroll
    for (int m = 0; m < 2; ++m)
#pragma unroll
      for (int r = 0; r < 4; ++r) {
        int row = rbase + m * 16 + lb * 4 + r;
        tls[row * T1_P + col] = (bf16)silu_f(acc[m][t][r] + bias);
      }
  }
  __syncthreads();

  zero_acc(acc);
  mm_layer<8>(tls + rbase * T1_P, T1_P, Wn2p, lane, nc0, acc);
#pragma unroll
  for (int t = 0; t < 4; ++t) {
    int col = (nc0 + t) * 16 + la;
    float bias = bn2[col];
#pragma unroll
    for (int m = 0; m < 2; ++m)
#pragma unroll
      for (int r = 0; r < 4; ++r) {
        long row = n0 + rbase + m * 16 + lb * 4 + r;
        if (row < NN)
          hout[row * HD + col] = h[row * HD + col] + acc[m][t][r] + bias;
      }
  }
}

extern "C" void kernel_launch(void* const* d_in, const int* in_sizes, int n_in,
                              void* d_out, int out_size, void* d_ws, size_t ws_size,
                              hipStream_t stream) {
  (void)in_sizes; (void)n_in; (void)out_size; (void)ws_size;
  const float* h   = (const float*)d_in[0];
  const float* x   = (const float*)d_in[1];
  const int*   ei  = (const int*)d_in[2];
  const float* ea  = (const float*)d_in[3];
  const float* We1 = (const float*)d_in[4];
  const float* be1 = (const float*)d_in[5];
  const float* We2 = (const float*)d_in[6];
  const float* be2 = (const float*)d_in[7];
  const float* Wn1 = (const float*)d_in[8];
  const float* bn1 = (const float*)d_in[9];
  const float* Wn2 = (const float*)d_in[10];
  const float* bn2 = (const float*)d_in[11];
  const float* Wc1 = (const float*)d_in[12];
  const float* bc1 = (const float*)d_in[13];
  const float* Wc2 = (const float*)d_in[14];

  float* hout = (float*)d_out;
  float* xout = hout + (long)NN * HD;

  char* ws = (char*)d_ws;
  bf16* m_i  = (bf16*)ws;                        // 25,600,000 B
  bf16* We1p = (bf16*)(ws + 25600000);           // 311,296 B
  bf16* We2p = (bf16*)(ws + 25911296);           // 131,072 B
  bf16* Wc1p = (bf16*)(ws + 26042368);           // 131,072 B
  bf16* Wn1p = (bf16*)(ws + 26173440);           // 262,144 B
  bf16* Wn2p = (bf16*)(ws + 26435584);           // 131,072 B

  prep_kernel<<<2048, 256, 0, stream>>>(x, We1, We2, Wc1, Wn1, Wn2,
                                        m_i, xout, We1p, We2p, Wc1p, Wn1p, Wn2p);
  edge_kernel<<<EE / EB, 512, 0, stream>>>(h, x, ei, ea, We1p, be1, We2p, be2,
                                           Wc1p, bc1, Wc2, m_i, xout);
  node_kernel<<<(NN + NB - 1) / NB, 512, 0, stream>>>(h, m_i, Wn1p, bn1, Wn2p, bn2, hout);
}

// Round 3
// 1585.929 us; speedup vs baseline: 1.1790x; 1.1790x over previous
//
#include <hip/hip_runtime.h>

#define NN 50000
#define EE 800000
#define HD 256

typedef __bf16 bf16;
typedef bf16 bf16x8 __attribute__((ext_vector_type(8)));
typedef bf16 bf16x4 __attribute__((ext_vector_type(4)));
typedef float f32x4 __attribute__((ext_vector_type(4)));

__device__ __forceinline__ float silu_f(float v) { return v / (1.f + __expf(-v)); }

// packed-weight linear index -> (k, col). Layout: [kc][nc][lane][r], r=0..7
__device__ __forceinline__ void pk_idx(int p, int& k, int& col) {
  int r = p & 7;
  int lane = (p >> 3) & 63;
  int nc = (p >> 9) & 15;
  int kc = p >> 13;
  k = kc * 32 + ((lane >> 4) << 3) + r;
  col = (nc << 4) + (lane & 15);
}

// bf16x2 packed atomic add (device scope) — fallback path only.
__device__ __forceinline__ void atomic_pk_add_bf16(bf16* addr, float a, float b) {
  union { bf16 h[2]; unsigned int u; } p;
  p.h[0] = (bf16)a; p.h[1] = (bf16)b;
  asm volatile("global_atomic_pk_add_bf16 %0, %1, off"
               :: "v"((unsigned long long)(uintptr_t)addr), "v"(p.u) : "memory");
}

// ---------------- prep: zero m_i+cnt, copy x->xout, pack weights -------------------
__global__ __launch_bounds__(256) void prep_kernel(
    const float* __restrict__ x,
    const float* __restrict__ We1, const float* __restrict__ We2,
    const float* __restrict__ Wc1, const float* __restrict__ Wn1,
    const float* __restrict__ Wn2,
    bf16* __restrict__ m_i, float* __restrict__ xout, int* __restrict__ cnt,
    bf16* __restrict__ We1p, bf16* __restrict__ We2p, bf16* __restrict__ Wc1p,
    bf16* __restrict__ Wn1p, bf16* __restrict__ Wn2p)
{
  const int stride = gridDim.x * blockDim.x;
  for (int i = blockIdx.x * blockDim.x + threadIdx.x; i < NN * HD / 2; i += stride) {
    ((unsigned int*)m_i)[i] = 0u;
    if (i < NN) cnt[i] = 0;
    if (i < 3 * NN) xout[i] = x[i];
    if (i < 19 * 8192) {  // We1 packed: K-order = h_src(256) h_dst(256) ea(64) dsq(1) zeros(31)
      int k, col; pk_idx(i, k, col);
      float v = 0.f;
      if (k < 512) v = We1[k * HD + col];
      else if (k < 576) v = We1[(k + 1) * HD + col];
      else if (k == 576) v = We1[512 * HD + col];
      We1p[i] = (bf16)v;
    }
    if (i < 8 * 8192) {
      int k, col; pk_idx(i, k, col);
      We2p[i] = (bf16)We2[k * HD + col];
      Wc1p[i] = (bf16)Wc1[k * HD + col];
      Wn2p[i] = (bf16)Wn2[k * HD + col];
    }
    if (i < 16 * 8192) {
      int k, col; pk_idx(i, k, col);
      Wn1p[i] = (bf16)Wn1[k * HD + col];
    }
  }
}

// ---------------- CSR build: histogram, scan, fill ---------------------------------
__global__ __launch_bounds__(256) void hist_kernel(const int* __restrict__ ei,
                                                   int* __restrict__ cnt) {
  int e = blockIdx.x * 256 + threadIdx.x;
  if (e < EE) atomicAdd(&cnt[ei[EE + e]], 1);
}

__global__ __launch_bounds__(1024) void scan_kernel(const int* __restrict__ cnt,
                                                    int* __restrict__ off,
                                                    int* __restrict__ cursor) {
  __shared__ int wsum[16];
  __shared__ int carry_s;
  const int tid = threadIdx.x, lane = tid & 63, w = tid >> 6;
  if (tid == 0) carry_s = 0;
  __syncthreads();
  for (int base = 0; base < NN; base += 1024) {
    int i = base + tid;
    int v = (i < NN) ? cnt[i] : 0;
    int sc = v;
    for (int d = 1; d < 64; d <<= 1) { int t = __shfl_up(sc, d); if (lane >= d) sc += t; }
    if (lane == 63) wsum[w] = sc;
    __syncthreads();
    if (w == 0) {
      int ws_ = (lane < 16) ? wsum[lane] : 0;
      for (int d = 1; d < 16; d <<= 1) { int t = __shfl_up(ws_, d); if (lane >= d) ws_ += t; }
      if (lane < 16) wsum[lane] = ws_;
    }
    __syncthreads();
    int woff = (w == 0) ? 0 : wsum[w - 1];
    int carry = carry_s;
    int incl = carry + woff + sc;
    if (i < NN) { off[i + 1] = incl; cursor[i] = incl - v; }
    __syncthreads();
    if (tid == 1023) carry_s = incl;
    __syncthreads();
  }
  if (threadIdx.x == 0) off[0] = 0;
}

__global__ __launch_bounds__(256) void fill_kernel(const int* __restrict__ ei,
                                                   int* __restrict__ cursor,
                                                   int* __restrict__ csr) {
  int e = blockIdx.x * 256 + threadIdx.x;
  if (e < EE) {
    int d = ei[EE + e];
    int slot = atomicAdd(&cursor[d], 1);
    csr[slot] = e;
  }
}

// ---------------- GEMM micro-tiles ------------------------------------------------
__device__ __forceinline__ void zero_acc24(f32x4 acc[2][4]) {
#pragma unroll
  for (int m = 0; m < 2; ++m)
#pragma unroll
    for (int t = 0; t < 4; ++t)
#pragma unroll
      for (int r = 0; r < 4; ++r) acc[m][t][r] = 0.f;
}
__device__ __forceinline__ void zero_acc42(f32x4 acc[4][2]) {
#pragma unroll
  for (int m = 0; m < 4; ++m)
#pragma unroll
    for (int t = 0; t < 2; ++t)
#pragma unroll
      for (int r = 0; r < 4; ++r) acc[m][t][r] = 0.f;
}

// 32 rows x 64 cols per wave (fallback + node kernel)
template <int KC>
__device__ __forceinline__ void mm_layer(const bf16* __restrict__ Asrc, int pitch,
                                         const bf16* __restrict__ Wp, int lane, int nc0,
                                         f32x4 acc[2][4])
{
  const int la = lane & 15, lb = lane >> 4;
#pragma unroll 2
  for (int kc = 0; kc < KC; ++kc) {
    bf16x8 a0 = *(const bf16x8*)&Asrc[la * pitch + kc * 32 + lb * 8];
    bf16x8 a1 = *(const bf16x8*)&Asrc[(16 + la) * pitch + kc * 32 + lb * 8];
    const bf16x8* wp = (const bf16x8*)Wp + ((kc * 16 + nc0) * 64 + lane);
#pragma unroll
    for (int t = 0; t < 4; ++t) {
      bf16x8 b = wp[t * 64];
      acc[0][t] = __builtin_amdgcn_mfma_f32_16x16x32_bf16(a0, b, acc[0][t], 0, 0, 0);
      acc[1][t] = __builtin_amdgcn_mfma_f32_16x16x32_bf16(a1, b, acc[1][t], 0, 0, 0);
    }
  }
}

// 64 rows x 32 cols per wave: B-fragments fetched once per block (8 waves cover 256 cols)
template <int KC>
__device__ __forceinline__ void mm64(const bf16* __restrict__ Asrc, int pitch,
                                     const bf16* __restrict__ Wp, int lane, int nc0,
                                     f32x4 acc[4][2])
{
  const int la = lane & 15, lb = lane >> 4;
#pragma unroll 2
  for (int kc = 0; kc < KC; ++kc) {
    bf16x8 a0 = *(const bf16x8*)&Asrc[la * pitch + kc * 32 + lb * 8];
    bf16x8 a1 = *(const bf16x8*)&Asrc[(16 + la) * pitch + kc * 32 + lb * 8];
    bf16x8 a2 = *(const bf16x8*)&Asrc[(32 + la) * pitch + kc * 32 + lb * 8];
    bf16x8 a3 = *(const bf16x8*)&Asrc[(48 + la) * pitch + kc * 32 + lb * 8];
    const bf16x8* wp = (const bf16x8*)Wp + ((kc * 16 + nc0) * 64 + lane);
#pragma unroll
    for (int t = 0; t < 2; ++t) {
      bf16x8 b = wp[t * 64];
      acc[0][t] = __builtin_amdgcn_mfma_f32_16x16x32_bf16(a0, b, acc[0][t], 0, 0, 0);
      acc[1][t] = __builtin_amdgcn_mfma_f32_16x16x32_bf16(a1, b, acc[1][t], 0, 0, 0);
      acc[2][t] = __builtin_amdgcn_mfma_f32_16x16x32_bf16(a2, b, acc[2][t], 0, 0, 0);
      acc[3][t] = __builtin_amdgcn_mfma_f32_16x16x32_bf16(a3, b, acc[3][t], 0, 0, 0);
    }
  }
}

constexpr int EB = 64;      // edges per block
constexpr int EIN_P = 616;  // 1232B rows (odd multiple of 16B)
constexpr int T1_P = 264;   // 528B rows

// ---------------- CSR-path edge kernel: streams m_ij + relw, NO fp atomics ----------
__global__ __launch_bounds__(512, 4) void edge_csr_kernel(
    const float* __restrict__ h, const float* __restrict__ x,
    const int* __restrict__ ei, const float* __restrict__ ea,
    const bf16* __restrict__ We1p, const float* __restrict__ be1,
    const bf16* __restrict__ We2p, const float* __restrict__ be2,
    const bf16* __restrict__ Wc1p, const float* __restrict__ bc1,
    const float* __restrict__ Wc2,
    bf16* __restrict__ m_ij, float4* __restrict__ relw)
{
  __shared__ __align__(16) bf16 ein[EB * EIN_P];
  __shared__ float rel0[EB], rel1[EB], rel2[EB];
  __shared__ float cw[EB];
  __shared__ int sidx[EB], didx[EB];
  bf16* const t1s = ein;

  const int tid = threadIdx.x;
  const int e0 = blockIdx.x * EB;

  if (tid < EB) {
    int e = e0 + tid;
    int s = ei[e], d = ei[EE + e];
    sidx[tid] = s; didx[tid] = d;
    float rx = x[3 * s + 0] - x[3 * d + 0];
    float ry = x[3 * s + 1] - x[3 * d + 1];
    float rz = x[3 * s + 2] - x[3 * d + 2];
    rel0[tid] = rx; rel1[tid] = ry; rel2[tid] = rz;
    cw[tid] = 0.f;
  }
  __syncthreads();

  for (int i = tid; i < EB * 64; i += 512) {
    int er = i >> 6, q = i & 63;
    float4 v = ((const float4*)h)[(long)sidx[er] * 64 + q];
    bf16x4 b; b[0] = (bf16)v.x; b[1] = (bf16)v.y; b[2] = (bf16)v.z; b[3] = (bf16)v.w;
    *(bf16x4*)&ein[er * EIN_P + q * 4] = b;
  }
  for (int i = tid; i < EB * 64; i += 512) {
    int er = i >> 6, q = i & 63;
    float4 v = ((const float4*)h)[(long)didx[er] * 64 + q];
    bf16x4 b; b[0] = (bf16)v.x; b[1] = (bf16)v.y; b[2] = (bf16)v.z; b[3] = (bf16)v.w;
    *(bf16x4*)&ein[er * EIN_P + 256 + q * 4] = b;
  }
  for (int i = tid; i < EB * 16; i += 512) {
    int er = i >> 4, q = i & 15;
    float4 v = ((const float4*)ea)[(long)(e0 + er) * 16 + q];
    bf16x4 b; b[0] = (bf16)v.x; b[1] = (bf16)v.y; b[2] = (bf16)v.z; b[3] = (bf16)v.w;
    *(bf16x4*)&ein[er * EIN_P + 512 + q * 4] = b;
  }
  if (tid < EB) {
    float dsq = rel0[tid] * rel0[tid] + rel1[tid] * rel1[tid] + rel2[tid] * rel2[tid];
    ein[tid * EIN_P + 576] = (bf16)dsq;
    for (int k2 = 577; k2 < 608; ++k2) ein[tid * EIN_P + k2] = (bf16)0.f;
  }
  __syncthreads();

  const int lane = tid & 63;
  const int wv = tid >> 6;
  const int la = lane & 15, lb = lane >> 4;
  const int nc0 = wv * 2;  // each wave: all 64 rows, 32-col slice

  f32x4 acc[4][2];

  // ---- layer 1 ----
  zero_acc42(acc);
  mm64<19>(ein, EIN_P, We1p, lane, nc0, acc);
  __syncthreads();  // done reading ein before t1s overwrites
#pragma unroll
  for (int t = 0; t < 2; ++t) {
    int col = (nc0 + t) * 16 + la;
    float bias = be1[col];
#pragma unroll
    for (int m = 0; m < 4; ++m)
#pragma unroll
      for (int r = 0; r < 4; ++r) {
        int row = m * 16 + lb * 4 + r;
        t1s[row * T1_P + col] = (bf16)silu_f(acc[m][t][r] + bias);
      }
  }
  __syncthreads();

  // ---- layer 2 (m_ij) ----
  zero_acc42(acc);
  mm64<8>(t1s, T1_P, We2p, lane, nc0, acc);
  __syncthreads();  // done reading t1s
#pragma unroll
  for (int t = 0; t < 2; ++t) {
    int col = (nc0 + t) * 16 + la;
    float bias = be2[col];
#pragma unroll
    for (int m = 0; m < 4; ++m)
#pragma unroll
      for (int r = 0; r < 4; ++r) {
        int row = m * 16 + lb * 4 + r;
        t1s[row * T1_P + col] = (bf16)silu_f(acc[m][t][r] + bias);
      }
  }
  __syncthreads();

  // coalesced m_ij stream-out (reads t1s; layer 3 also only reads t1s)
  for (int i = tid; i < EB * 32; i += 512) {
    int er = i >> 5, q = i & 31;
    *(bf16x8*)&m_ij[(long)(e0 + er) * HD + q * 8] = *(const bf16x8*)&t1s[er * T1_P + q * 8];
  }

  // ---- layer 3 (coord weight) ----
  zero_acc42(acc);
  mm64<8>(t1s, T1_P, Wc1p, lane, nc0, acc);
  float pr[4][4];
#pragma unroll
  for (int m = 0; m < 4; ++m)
#pragma unroll
    for (int r = 0; r < 4; ++r) pr[m][r] = 0.f;
#pragma unroll
  for (int t = 0; t < 2; ++t) {
    int col = (nc0 + t) * 16 + la;
    float bias = bc1[col];
    float wc = Wc2[col];
#pragma unroll
    for (int m = 0; m < 4; ++m)
#pragma unroll
      for (int r = 0; r < 4; ++r)
        pr[m][r] += silu_f(acc[m][t][r] + bias) * wc;
  }
#pragma unroll
  for (int m = 0; m < 4; ++m)
#pragma unroll
    for (int r = 0; r < 4; ++r) {
      float v = pr[m][r];
      v += __shfl_xor(v, 1);
      v += __shfl_xor(v, 2);
      v += __shfl_xor(v, 4);
      v += __shfl_xor(v, 8);
      if (la == 0) atomicAdd(&cw[m * 16 + lb * 4 + r], v);  // LDS atomic
    }
  __syncthreads();

  if (tid < EB) {
    float4 o; o.x = rel0[tid]; o.y = rel1[tid]; o.z = rel2[tid]; o.w = cw[tid];
    relw[e0 + tid] = o;
  }
}

// ---------------- gather: per-node fp32 reduction of m_ij and coord update ---------
__global__ __launch_bounds__(512) void gather_kernel(
    const float* __restrict__ x,
    const bf16* __restrict__ m_ij, const float4* __restrict__ relw,
    const int* __restrict__ off, const int* __restrict__ csr,
    bf16* __restrict__ m_i, float* __restrict__ xout)
{
  const int lane = threadIdx.x & 63;
  const int wv = threadIdx.x >> 6;
  const int n = blockIdx.x * 8 + wv;
  if (n >= NN) return;
  const int s = off[n];
  const int epc = off[n + 1] - s;

  float a0 = 0.f, a1 = 0.f, a2 = 0.f, a3 = 0.f;
#pragma unroll 2
  for (int j = 0; j < epc; ++j) {
    int eid = csr[s + j];
    bf16x4 v = *(const bf16x4*)&m_ij[(long)eid * HD + lane * 4];
    a0 += (float)v[0]; a1 += (float)v[1]; a2 += (float)v[2]; a3 += (float)v[3];
  }
  bf16x4 o; o[0] = (bf16)a0; o[1] = (bf16)a1; o[2] = (bf16)a2; o[3] = (bf16)a3;
  *(bf16x4*)&m_i[(long)n * HD + lane * 4] = o;

  float sx = 0.f, sy = 0.f, sz = 0.f;
  for (int j = lane; j < epc; j += 64) {
    int eid = csr[s + j];
    float4 rw = relw[eid];
    sx += rw.x * rw.w; sy += rw.y * rw.w; sz += rw.z * rw.w;
  }
  for (int d = 1; d < 64; d <<= 1) {
    sx += __shfl_xor(sx, d); sy += __shfl_xor(sy, d); sz += __shfl_xor(sz, d);
  }
  if (lane == 0) {
    xout[3 * n + 0] = x[3 * n + 0] + sx;
    xout[3 * n + 1] = x[3 * n + 1] + sy;
    xout[3 * n + 2] = x[3 * n + 2] + sz;
  }
}

// ---------------- fallback edge kernel (R2, atomic path) ---------------------------
__global__ __launch_bounds__(512, 4) void edge_atomic_kernel(
    const float* __restrict__ h, const float* __restrict__ x,
    const int* __restrict__ ei, const float* __restrict__ ea,
    const bf16* __restrict__ We1p, const float* __restrict__ be1,
    const bf16* __restrict__ We2p, const float* __restrict__ be2,
    const bf16* __restrict__ Wc1p, const float* __restrict__ bc1,
    const float* __restrict__ Wc2,
    bf16* __restrict__ m_i, float* __restrict__ xout)
{
  __shared__ __align__(16) bf16 ein[EB * EIN_P];
  __shared__ float rel0[EB], rel1[EB], rel2[EB];
  __shared__ float cw[EB];
  __shared__ int sidx[EB], didx[EB];
  bf16* const t1s = ein;

  const int tid = threadIdx.x;
  const int e0 = blockIdx.x * EB;

  if (tid < EB) {
    int e = e0 + tid;
    int s = ei[e], d = ei[EE + e];
    sidx[tid] = s; didx[tid] = d;
    float rx = x[3 * s + 0] - x[3 * d + 0];
    float ry = x[3 * s + 1] - x[3 * d + 1];
    float rz = x[3 * s + 2] - x[3 * d + 2];
    rel0[tid] = rx; rel1[tid] = ry; rel2[tid] = rz;
    cw[tid] = 0.f;
  }
  __syncthreads();
  for (int i = tid; i < EB * 64; i += 512) {
    int er = i >> 6, q = i & 63;
    float4 v = ((const float4*)h)[(long)sidx[er] * 64 + q];
    bf16x4 b; b[0] = (bf16)v.x; b[1] = (bf16)v.y; b[2] = (bf16)v.z; b[3] = (bf16)v.w;
    *(bf16x4*)&ein[er * EIN_P + q * 4] = b;
  }
  for (int i = tid; i < EB * 64; i += 512) {
    int er = i >> 6, q = i & 63;
    float4 v = ((const float4*)h)[(long)didx[er] * 64 + q];
    bf16x4 b; b[0] = (bf16)v.x; b[1] = (bf16)v.y; b[2] = (bf16)v.z; b[3] = (bf16)v.w;
    *(bf16x4*)&ein[er * EIN_P + 256 + q * 4] = b;
  }
  for (int i = tid; i < EB * 16; i += 512) {
    int er = i >> 4, q = i & 15;
    float4 v = ((const float4*)ea)[(long)(e0 + er) * 16 + q];
    bf16x4 b; b[0] = (bf16)v.x; b[1] = (bf16)v.y; b[2] = (bf16)v.z; b[3] = (bf16)v.w;
    *(bf16x4*)&ein[er * EIN_P + 512 + q * 4] = b;
  }
  if (tid < EB) {
    float dsq = rel0[tid] * rel0[tid] + rel1[tid] * rel1[tid] + rel2[tid] * rel2[tid];
    ein[tid * EIN_P + 576] = (bf16)dsq;
    for (int k2 = 577; k2 < 608; ++k2) ein[tid * EIN_P + k2] = (bf16)0.f;
  }
  __syncthreads();

  const int lane = tid & 63;
  const int wv = tid >> 6;
  const int la = lane & 15, lb = lane >> 4;
  const int rbase = (wv >> 2) * 32;
  const int nc0 = (wv & 3) * 4;

  f32x4 acc[2][4];
  zero_acc24(acc);
  mm_layer<19>(ein + rbase * EIN_P, EIN_P, We1p, lane, nc0, acc);
  __syncthreads();
#pragma unroll
  for (int t = 0; t < 4; ++t) {
    int col = (nc0 + t) * 16 + la;
    float bias = be1[col];
#pragma unroll
    for (int m = 0; m < 2; ++m)
#pragma unroll
      for (int r = 0; r < 4; ++r) {
        int row = rbase + m * 16 + lb * 4 + r;
        t1s[row * T1_P + col] = (bf16)silu_f(acc[m][t][r] + bias);
      }
  }
  __syncthreads();

  zero_acc24(acc);
  mm_layer<8>(t1s + rbase * T1_P, T1_P, We2p, lane, nc0, acc);
  int dr[2][4];
#pragma unroll
  for (int m = 0; m < 2; ++m)
#pragma unroll
    for (int r = 0; r < 4; ++r) dr[m][r] = didx[rbase + m * 16 + lb * 4 + r];
  __syncthreads();
#pragma unroll
  for (int t = 0; t < 4; ++t) {
    int col = (nc0 + t) * 16 + la;
    float bias = be2[col];
#pragma unroll
    for (int m = 0; m < 2; ++m)
#pragma unroll
      for (int r = 0; r < 4; ++r) {
        int row = rbase + m * 16 + lb * 4 + r;
        float mv = silu_f(acc[m][t][r] + bias);
        t1s[row * T1_P + col] = (bf16)mv;
        float mo = __shfl_xor(mv, 1);
        if ((la & 1) == 0)
          atomic_pk_add_bf16(&m_i[(long)dr[m][r] * HD + col], mv, mo);
      }
  }
  __syncthreads();

  zero_acc24(acc);
  mm_layer<8>(t1s + rbase * T1_P, T1_P, Wc1p, lane, nc0, acc);
  float pr[2][4];
#pragma unroll
  for (int m = 0; m < 2; ++m)
#pragma unroll
    for (int r = 0; r < 4; ++r) pr[m][r] = 0.f;
#pragma unroll
  for (int t = 0; t < 4; ++t) {
    int col = (nc0 + t) * 16 + la;
    float bias = bc1[col];
    float wc = Wc2[col];
#pragma unroll
    for (int m = 0; m < 2; ++m)
#pragma unroll
      for (int r = 0; r < 4; ++r)
        pr[m][r] += silu_f(acc[m][t][r] + bias) * wc;
  }
#pragma unroll
  for (int m = 0; m < 2; ++m)
#pragma unroll
    for (int r = 0; r < 4; ++r) {
      float v = pr[m][r];
      v += __shfl_xor(v, 1);
      v += __shfl_xor(v, 2);
      v += __shfl_xor(v, 4);
      v += __shfl_xor(v, 8);
      if (la == 0) atomicAdd(&cw[rbase + m * 16 + lb * 4 + r], v);
    }
  __syncthreads();

  if (tid < EB) {
    float wgt = cw[tid];
    int d = didx[tid];
    atomicAdd(&xout[3 * d + 0], rel0[tid] * wgt);
    atomicAdd(&xout[3 * d + 1], rel1[tid] * wgt);
    atomicAdd(&xout[3 * d + 2], rel2[tid] * wgt);
  }
}

constexpr int NB = 64;
constexpr int NIN_P = 520;

// ---------------- node kernel: h_out = h + node_mlp([h, m_i]) ----------------------
__global__ __launch_bounds__(512, 4) void node_kernel(
    const float* __restrict__ h, const bf16* __restrict__ m_i,
    const bf16* __restrict__ Wn1p, const float* __restrict__ bn1,
    const bf16* __restrict__ Wn2p, const float* __restrict__ bn2,
    float* __restrict__ hout)
{
  __shared__ __align__(16) bf16 nin[NB * NIN_P];
  bf16* const tls = nin;
  const int tid = threadIdx.x;
  const long n0 = (long)blockIdx.x * NB;

  for (int i = tid; i < NB * 64; i += 512) {
    int nr = i >> 6, q = i & 63;
    long row = n0 + nr; if (row >= NN) row = NN - 1;
    float4 v = ((const float4*)h)[row * 64 + q];
    bf16x4 b; b[0] = (bf16)v.x; b[1] = (bf16)v.y; b[2] = (bf16)v.z; b[3] = (bf16)v.w;
    *(bf16x4*)&nin[nr * NIN_P + q * 4] = b;
  }
  for (int i = tid; i < NB * 32; i += 512) {
    int nr = i >> 5, q = i & 31;
    long row = n0 + nr; if (row >= NN) row = NN - 1;
    *(bf16x8*)&nin[nr * NIN_P + 256 + q * 8] = *(const bf16x8*)&m_i[row * HD + q * 8];
  }
  __syncthreads();

  const int lane = tid & 63;
  const int wv = tid >> 6;
  const int la = lane & 15, lb = lane >> 4;
  const int rbase = (wv >> 2) * 32;
  const int nc0 = (wv & 3) * 4;

  f32x4 acc[2][4];
  zero_acc24(acc);
  mm_layer<16>(nin + rbase * NIN_P, NIN_P, Wn1p, lane, nc0, acc);
  __syncthreads();
#pragma unroll
  for (int t = 0; t < 4; ++t) {
    int col = (nc0 + t) * 16 + la;
    float bias = bn1[col];
#pragma unroll
    for (int m = 0; m < 2; ++m)
#pragma unroll
      for (int r = 0; r < 4; ++r) {
        int row = rbase + m * 16 + lb * 4 + r;
        tls[row * T1_P + col] = (bf16)silu_f(acc[m][t][r] + bias);
      }
  }
  __syncthreads();

  zero_acc24(acc);
  mm_layer<8>(tls + rbase * T1_P, T1_P, Wn2p, lane, nc0, acc);
#pragma unroll
  for (int t = 0; t < 4; ++t) {
    int col = (nc0 + t) * 16 + la;
    float bias = bn2[col];
#pragma unroll
    for (int m = 0; m < 2; ++m)
#pragma unroll
      for (int r = 0; r < 4; ++r) {
        long row = n0 + rbase + m * 16 + lb * 4 + r;
        if (row < NN)
          hout[row * HD + col] = h[row * HD + col] + acc[m][t][r] + bias;
      }
  }
}

extern "C" void kernel_launch(void* const* d_in, const int* in_sizes, int n_in,
                              void* d_out, int out_size, void* d_ws, size_t ws_size,
                              hipStream_t stream) {
  (void)in_sizes; (void)n_in; (void)out_size;
  const float* h   = (const float*)d_in[0];
  const float* x   = (const float*)d_in[1];
  const int*   ei  = (const int*)d_in[2];
  const float* ea  = (const float*)d_in[3];
  const float* We1 = (const float*)d_in[4];
  const float* be1 = (const float*)d_in[5];
  const float* We2 = (const float*)d_in[6];
  const float* be2 = (const float*)d_in[7];
  const float* Wn1 = (const float*)d_in[8];
  const float* bn1 = (const float*)d_in[9];
  const float* Wn2 = (const float*)d_in[10];
  const float* bn2 = (const float*)d_in[11];
  const float* Wc1 = (const float*)d_in[12];
  const float* bc1 = (const float*)d_in[13];
  const float* Wc2 = (const float*)d_in[14];

  float* hout = (float*)d_out;
  float* xout = hout + (long)NN * HD;
  char* ws = (char*)d_ws;

  const size_t NEED = 452898048ull;
  if (ws_size >= NEED) {
    // ---- CSR path ----
    bf16*   m_ij  = (bf16*)(ws + 0);             // 409,600,000
    float4* relw  = (float4*)(ws + 409600000);   //  12,800,000
    int*    csr   = (int*)(ws + 422400000);      //   3,200,000
    int*    cnt   = (int*)(ws + 425600000);      //     200,000
    int*    offA  = (int*)(ws + 425800000);      //     200,004
    int*    cur   = (int*)(ws + 426000256);      //     200,000
    bf16*   m_i   = (bf16*)(ws + 426200320);     //  25,600,000
    bf16*   We1p  = (bf16*)(ws + 451800320);
    bf16*   We2p  = (bf16*)(ws + 452111616);
    bf16*   Wc1p  = (bf16*)(ws + 452242688);
    bf16*   Wn1p  = (bf16*)(ws + 452373760);
    bf16*   Wn2p  = (bf16*)(ws + 452635904);

    prep_kernel<<<2048, 256, 0, stream>>>(x, We1, We2, Wc1, Wn1, Wn2,
                                          m_i, xout, cnt, We1p, We2p, Wc1p, Wn1p, Wn2p);
    hist_kernel<<<(EE + 255) / 256, 256, 0, stream>>>(ei, cnt);
    scan_kernel<<<1, 1024, 0, stream>>>(cnt, offA, cur);
    fill_kernel<<<(EE + 255) / 256, 256, 0, stream>>>(ei, cur, csr);
    edge_csr_kernel<<<EE / EB, 512, 0, stream>>>(h, x, ei, ea, We1p, be1, We2p, be2,
                                                 Wc1p, bc1, Wc2, m_ij, relw);
    gather_kernel<<<(NN + 7) / 8, 512, 0, stream>>>(x, m_ij, relw, offA, csr, m_i, xout);
    node_kernel<<<(NN + NB - 1) / NB, 512, 0, stream>>>(h, m_i, Wn1p, bn1, Wn2p, bn2, hout);
  } else {
    // ---- fallback: R2 atomic path ----
    bf16* m_i  = (bf16*)ws;
    int*  cnt  = (int*)(ws + 25600000);          // dummy for prep
    bf16* We1p = (bf16*)(ws + 25800192);
    bf16* We2p = (bf16*)(ws + 26111488);
    bf16* Wc1p = (bf16*)(ws + 26242560);
    bf16* Wn1p = (bf16*)(ws + 26373632);
    bf16* Wn2p = (bf16*)(ws + 26635776);

    prep_kernel<<<2048, 256, 0, stream>>>(x, We1, We2, Wc1, Wn1, Wn2,
                                          m_i, xout, cnt, We1p, We2p, Wc1p, Wn1p, Wn2p);
    edge_atomic_kernel<<<EE / EB, 512, 0, stream>>>(h, x, ei, ea, We1p, be1, We2p, be2,
                                                    Wc1p, bc1, Wc2, m_i, xout);
    node_kernel<<<(NN + NB - 1) / NB, 512, 0, stream>>>(h, m_i, Wn1p, bn1, Wn2p, bn2, hout);
  }
}

// Round 7
// 1441.387 us; speedup vs baseline: 1.2972x; 1.1003x over previous
//
#include <hip/hip_runtime.h>

#define NN 50000
#define EE 800000
#define HD 256

typedef __bf16 bf16;
typedef bf16 bf16x8 __attribute__((ext_vector_type(8)));
typedef bf16 bf16x4 __attribute__((ext_vector_type(4)));
typedef float f32x4 __attribute__((ext_vector_type(4)));

__device__ __forceinline__ float silu_f(float v) { return v / (1.f + __expf(-v)); }

// packed-weight linear index -> (k, col). Layout: [kc][nc][lane][r], r=0..7
__device__ __forceinline__ void pk_idx(int p, int& k, int& col) {
  int r = p & 7;
  int lane = (p >> 3) & 63;
  int nc = (p >> 9) & 15;
  int kc = p >> 13;
  k = kc * 32 + ((lane >> 4) << 3) + r;
  col = (nc << 4) + (lane & 15);
}

// bf16x2 packed atomic add (device scope) — atomic fallback path only.
__device__ __forceinline__ void atomic_pk_add_bf16(bf16* addr, float a, float b) {
  union { bf16 h[2]; unsigned int u; } p;
  p.h[0] = (bf16)a; p.h[1] = (bf16)b;
  asm volatile("global_atomic_pk_add_bf16 %0, %1, off"
               :: "v"((unsigned long long)(uintptr_t)addr), "v"(p.u) : "memory");
}

// ---------------- prep: zero m_i+cnt, copy x->xout, pack weights -------------------
__global__ __launch_bounds__(256) void prep_kernel(
    const float* __restrict__ x,
    const float* __restrict__ We1, const float* __restrict__ We2,
    const float* __restrict__ Wc1, const float* __restrict__ Wn1,
    const float* __restrict__ Wn2,
    bf16* __restrict__ m_i, float* __restrict__ xout, int* __restrict__ cnt,
    bf16* __restrict__ We1f, bf16* __restrict__ We2p, bf16* __restrict__ Wc1p,
    bf16* __restrict__ Wn1p, bf16* __restrict__ Wn2p,
    bf16* __restrict__ Ws1p, bf16* __restrict__ Wd1p, bf16* __restrict__ We1e,
    int pack_pre)
{
  const int stride = gridDim.x * blockDim.x;
  for (int i = blockIdx.x * blockDim.x + threadIdx.x; i < NN * HD / 2; i += stride) {
    ((unsigned int*)m_i)[i] = 0u;
    if (i < NN) cnt[i] = 0;
    if (i < 3 * NN) xout[i] = x[i];
    if (i < 19 * 8192) {  // full We1 pack (atomic/mid paths): K = hs(256) hd(256) ea(64) dsq(1) z(31)
      int k, col; pk_idx(i, k, col);
      float v = 0.f;
      if (k < 512) v = We1[k * HD + col];
      else if (k < 576) v = We1[(k + 1) * HD + col];
      else if (k == 576) v = We1[512 * HD + col];
      We1f[i] = (bf16)v;
    }
    if (i < 8 * 8192) {
      int k, col; pk_idx(i, k, col);
      We2p[i] = (bf16)We2[k * HD + col];
      Wc1p[i] = (bf16)Wc1[k * HD + col];
      Wn2p[i] = (bf16)Wn2[k * HD + col];
      if (pack_pre) {
        Ws1p[i] = (bf16)We1[k * HD + col];            // h_src rows 0..255
        Wd1p[i] = (bf16)We1[(256 + k) * HD + col];    // h_dst rows 256..511
      }
    }
    if (i < 16 * 8192) {
      int k, col; pk_idx(i, k, col);
      Wn1p[i] = (bf16)Wn1[k * HD + col];
    }
    if (pack_pre && i < 3 * 8192) {  // ea-only We1: K = ea(64) dsq(1) zeros(31)
      int k, col; pk_idx(i, k, col);
      float v = 0.f;
      if (k < 64) v = We1[(513 + k) * HD + col];
      else if (k == 64) v = We1[512 * HD + col];
      We1e[i] = (bf16)v;
    }
  }
}

// ---------------- CSR build: histogram, scan, fill (eslot) -------------------------
__global__ __launch_bounds__(256) void hist_kernel(const int* __restrict__ ei,
                                                   int* __restrict__ cnt) {
  int e = blockIdx.x * 256 + threadIdx.x;
  if (e < EE) atomicAdd(&cnt[ei[EE + e]], 1);
}

__global__ __launch_bounds__(1024) void scan_kernel(const int* __restrict__ cnt,
                                                    int* __restrict__ off,
                                                    int* __restrict__ cursor) {
  __shared__ int wsum[16];
  __shared__ int carry_s;
  const int tid = threadIdx.x, lane = tid & 63, w = tid >> 6;
  if (tid == 0) carry_s = 0;
  __syncthreads();
  for (int base = 0; base < NN; base += 1024) {
    int i = base + tid;
    int v = (i < NN) ? cnt[i] : 0;
    int sc = v;
    for (int d = 1; d < 64; d <<= 1) { int t = __shfl_up(sc, d); if (lane >= d) sc += t; }
    if (lane == 63) wsum[w] = sc;
    __syncthreads();
    if (w == 0) {
      int ws_ = (lane < 16) ? wsum[lane] : 0;
      for (int d = 1; d < 16; d <<= 1) { int t = __shfl_up(ws_, d); if (lane >= d) ws_ += t; }
      if (lane < 16) wsum[lane] = ws_;
    }
    __syncthreads();
    int woff = (w == 0) ? 0 : wsum[w - 1];
    int carry = carry_s;
    int incl = carry + woff + sc;
    if (i < NN) { off[i + 1] = incl; cursor[i] = incl - v; }
    __syncthreads();
    if (tid == 1023) carry_s = incl;
    __syncthreads();
  }
  if (threadIdx.x == 0) off[0] = 0;
}

__global__ __launch_bounds__(256) void fill_kernel(const int* __restrict__ ei,
                                                   int* __restrict__ cursor,
                                                   int* __restrict__ eslot) {
  int e = blockIdx.x * 256 + threadIdx.x;
  if (e < EE) {
    int d = ei[EE + e];
    int slot = atomicAdd(&cursor[d], 1);
    eslot[e] = slot;
  }
}

// ---------------- GEMM micro-tiles ------------------------------------------------
__device__ __forceinline__ void zero_acc24(f32x4 acc[2][4]) {
#pragma unroll
  for (int m = 0; m < 2; ++m)
#pragma unroll
    for (int t = 0; t < 4; ++t)
#pragma unroll
      for (int r = 0; r < 4; ++r) acc[m][t][r] = 0.f;
}
__device__ __forceinline__ void zero_acc42(f32x4 acc[4][2]) {
#pragma unroll
  for (int m = 0; m < 4; ++m)
#pragma unroll
    for (int t = 0; t < 2; ++t)
#pragma unroll
      for (int r = 0; r < 4; ++r) acc[m][t][r] = 0.f;
}

// 32 rows x 64 cols per wave (atomic fallback + node kernel)
template <int KC>
__device__ __forceinline__ void mm_layer(const bf16* __restrict__ Asrc, int pitch,
                                         const bf16* __restrict__ Wp, int lane, int nc0,
                                         f32x4 acc[2][4])
{
  const int la = lane & 15, lb = lane >> 4;
#pragma unroll 2
  for (int kc = 0; kc < KC; ++kc) {
    bf16x8 a0 = *(const bf16x8*)&Asrc[la * pitch + kc * 32 + lb * 8];
    bf16x8 a1 = *(const bf16x8*)&Asrc[(16 + la) * pitch + kc * 32 + lb * 8];
    const bf16x8* wp = (const bf16x8*)Wp + ((kc * 16 + nc0) * 64 + lane);
#pragma unroll
    for (int t = 0; t < 4; ++t) {
      bf16x8 b = wp[t * 64];
      acc[0][t] = __builtin_amdgcn_mfma_f32_16x16x32_bf16(a0, b, acc[0][t], 0, 0, 0);
      acc[1][t] = __builtin_amdgcn_mfma_f32_16x16x32_bf16(a1, b, acc[1][t], 0, 0, 0);
    }
  }
}

// 64 rows x 32 cols per wave: B-fragments fetched once per block
template <int KC>
__device__ __forceinline__ void mm64(const bf16* __restrict__ Asrc, int pitch,
                                     const bf16* __restrict__ Wp, int lane, int nc0,
                                     f32x4 acc[4][2])
{
  const int la = lane & 15, lb = lane >> 4;
#pragma unroll 2
  for (int kc = 0; kc < KC; ++kc) {
    bf16x8 a0 = *(const bf16x8*)&Asrc[la * pitch + kc * 32 + lb * 8];
    bf16x8 a1 = *(const bf16x8*)&Asrc[(16 + la) * pitch + kc * 32 + lb * 8];
    bf16x8 a2 = *(const bf16x8*)&Asrc[(32 + la) * pitch + kc * 32 + lb * 8];
    bf16x8 a3 = *(const bf16x8*)&Asrc[(48 + la) * pitch + kc * 32 + lb * 8];
    const bf16x8* wp = (const bf16x8*)Wp + ((kc * 16 + nc0) * 64 + lane);
#pragma unroll
    for (int t = 0; t < 2; ++t) {
      bf16x8 b = wp[t * 64];
      acc[0][t] = __builtin_amdgcn_mfma_f32_16x16x32_bf16(a0, b, acc[0][t], 0, 0, 0);
      acc[1][t] = __builtin_amdgcn_mfma_f32_16x16x32_bf16(a1, b, acc[1][t], 0, 0, 0);
      acc[2][t] = __builtin_amdgcn_mfma_f32_16x16x32_bf16(a2, b, acc[2][t], 0, 0, 0);
      acc[3][t] = __builtin_amdgcn_mfma_f32_16x16x32_bf16(a3, b, acc[3][t], 0, 0, 0);
    }
  }
}

constexpr int EB = 64;      // edges per block
constexpr int EA_P = 104;   // ea-tile pitch: 96 used, 208B = 13*16B (odd)
constexpr int EIN_P = 616;  // full-input pitch (fallback paths)
constexpr int T1_P = 264;   // 528B rows

// ---------------- pre kernel: pre_s = h@We1_top, pre_d = h@We1_mid (bf16 out) ------
__global__ __launch_bounds__(512, 4) void pre_kernel(
    const float* __restrict__ h,
    const bf16* __restrict__ Ws1p, const bf16* __restrict__ Wd1p,
    bf16* __restrict__ pre_s, bf16* __restrict__ pre_d)
{
  __shared__ __align__(16) bf16 nin[64 * T1_P];
  const int tid = threadIdx.x;
  const long n0 = (long)blockIdx.x * 64;

  for (int i = tid; i < 64 * 64; i += 512) {
    int nr = i >> 6, q = i & 63;
    long row = n0 + nr; if (row >= NN) row = NN - 1;
    float4 v = ((const float4*)h)[row * 64 + q];
    bf16x4 b; b[0] = (bf16)v.x; b[1] = (bf16)v.y; b[2] = (bf16)v.z; b[3] = (bf16)v.w;
    *(bf16x4*)&nin[nr * T1_P + q * 4] = b;
  }
  __syncthreads();

  const int lane = tid & 63;
  const int wv = tid >> 6;
  const int la = lane & 15, lb = lane >> 4;
  const int nc0 = wv * 2;

  f32x4 acc[4][2];
  zero_acc42(acc);
  mm64<8>(nin, T1_P, Ws1p, lane, nc0, acc);
#pragma unroll
  for (int t = 0; t < 2; ++t) {
    int col = (nc0 + t) * 16 + la;
#pragma unroll
    for (int m = 0; m < 4; ++m)
#pragma unroll
      for (int r = 0; r < 4; ++r) {
        long g = n0 + m * 16 + lb * 4 + r;
        if (g < NN) pre_s[g * HD + col] = (bf16)acc[m][t][r];
      }
  }
  zero_acc42(acc);
  mm64<8>(nin, T1_P, Wd1p, lane, nc0, acc);
#pragma unroll
  for (int t = 0; t < 2; ++t) {
    int col = (nc0 + t) * 16 + la;
#pragma unroll
    for (int m = 0; m < 4; ++m)
#pragma unroll
      for (int r = 0; r < 4; ++r) {
        long g = n0 + m * 16 + lb * 4 + r;
        if (g < NN) pre_d[g * HD + col] = (bf16)acc[m][t][r];
      }
  }
}

// ---------------- NEW edge kernel: K=96 layer-1 + pre gather, slot-ordered out -----
__global__ __launch_bounds__(512, 6) void edge_pre_kernel(
    const float* __restrict__ x,
    const int* __restrict__ ei, const int* __restrict__ eslot,
    const float* __restrict__ ea,
    const bf16* __restrict__ pre_s, const bf16* __restrict__ pre_d,
    const bf16* __restrict__ We1e, const float* __restrict__ be1,
    const bf16* __restrict__ We2p, const float* __restrict__ be2,
    const bf16* __restrict__ Wc1p, const float* __restrict__ bc1,
    const float* __restrict__ Wc2,
    bf16* __restrict__ m_ij, float4* __restrict__ relw)
{
  __shared__ __align__(16) bf16 eina[EB * EA_P];  // 13.3 KB
  __shared__ __align__(16) bf16 t1s[EB * T1_P];   // 33.8 KB (t1 then m_ij)
  __shared__ float rel0[EB], rel1[EB], rel2[EB];
  __shared__ float cw[EB];
  __shared__ int sidx[EB], didx[EB], sslot[EB];

  const int tid = threadIdx.x;
  const int e0 = blockIdx.x * EB;

  if (tid < EB) {
    int e = e0 + tid;
    int s = ei[e], d = ei[EE + e];
    sidx[tid] = s; didx[tid] = d; sslot[tid] = eslot[e];
    float rx = x[3 * s + 0] - x[3 * d + 0];
    float ry = x[3 * s + 1] - x[3 * d + 1];
    float rz = x[3 * s + 2] - x[3 * d + 2];
    rel0[tid] = rx; rel1[tid] = ry; rel2[tid] = rz;
    float dsq = rx * rx + ry * ry + rz * rz;
    eina[tid * EA_P + 64] = (bf16)dsq;
#pragma unroll
    for (int k2 = 65; k2 < 96; ++k2) eina[tid * EA_P + k2] = (bf16)0.f;
    cw[tid] = 0.f;
  }
  // edge_attr gather: 2 iters/thread
  for (int i = tid; i < EB * 16; i += 512) {
    int er = i >> 4, q = i & 15;
    float4 v = ((const float4*)ea)[(long)(e0 + er) * 16 + q];
    bf16x4 b; b[0] = (bf16)v.x; b[1] = (bf16)v.y; b[2] = (bf16)v.z; b[3] = (bf16)v.w;
    *(bf16x4*)&eina[er * EA_P + q * 4] = b;
  }
  __syncthreads();

  const int lane = tid & 63;
  const int wv = tid >> 6;
  const int la = lane & 15, lb = lane >> 4;
  const int nc0 = wv * 2;  // 32-col slice per wave, all 64 rows

  f32x4 acc[4][2];

  // ---- layer 1: ea@We1_ea (K=96) + pre_s[s] + pre_d[d] + be1 ----
  zero_acc42(acc);
  mm64<3>(eina, EA_P, We1e, lane, nc0, acc);
#pragma unroll
  for (int t = 0; t < 2; ++t) {
    int col = (nc0 + t) * 16 + la;
    float bias = be1[col];
#pragma unroll
    for (int m = 0; m < 4; ++m)
#pragma unroll
      for (int r = 0; r < 4; ++r) {
        int row = m * 16 + lb * 4 + r;
        float v = acc[m][t][r] + bias
                + (float)pre_s[(long)sidx[row] * HD + col]
                + (float)pre_d[(long)didx[row] * HD + col];
        t1s[row * T1_P + col] = (bf16)silu_f(v);
      }
  }
  __syncthreads();

  // ---- layer 2 (m_ij) ----
  zero_acc42(acc);
  mm64<8>(t1s, T1_P, We2p, lane, nc0, acc);
  __syncthreads();  // all waves done reading t1 before m_ij overlays it
#pragma unroll
  for (int t = 0; t < 2; ++t) {
    int col = (nc0 + t) * 16 + la;
    float bias = be2[col];
#pragma unroll
    for (int m = 0; m < 4; ++m)
#pragma unroll
      for (int r = 0; r < 4; ++r) {
        int row = m * 16 + lb * 4 + r;
        t1s[row * T1_P + col] = (bf16)silu_f(acc[m][t][r] + bias);
      }
  }
  __syncthreads();

  // slot-ordered m_ij scatter (coalesced 512B rows; gather will stream)
  for (int i = tid; i < EB * 32; i += 512) {
    int er = i >> 5, q = i & 31;
    *(bf16x8*)&m_ij[(long)sslot[er] * HD + q * 8] = *(const bf16x8*)&t1s[er * T1_P + q * 8];
  }

  // ---- layer 3 (coord weight); reads t1s only, concurrent with stream-out ----
  zero_acc42(acc);
  mm64<8>(t1s, T1_P, Wc1p, lane, nc0, acc);
  float pr[4][4];
#pragma unroll
  for (int m = 0; m < 4; ++m)
#pragma unroll
    for (int r = 0; r < 4; ++r) pr[m][r] = 0.f;
#pragma unroll
  for (int t = 0; t < 2; ++t) {
    int col = (nc0 + t) * 16 + la;
    float bias = bc1[col];
    float wc = Wc2[col];
#pragma unroll
    for (int m = 0; m < 4; ++m)
#pragma unroll
      for (int r = 0; r < 4; ++r)
        pr[m][r] += silu_f(acc[m][t][r] + bias) * wc;
  }
#pragma unroll
  for (int m = 0; m < 4; ++m)
#pragma unroll
    for (int r = 0; r < 4; ++r) {
      float v = pr[m][r];
      v += __shfl_xor(v, 1);
      v += __shfl_xor(v, 2);
      v += __shfl_xor(v, 4);
      v += __shfl_xor(v, 8);
      if (la == 0) atomicAdd(&cw[m * 16 + lb * 4 + r], v);  // LDS atomic
    }
  __syncthreads();

  if (tid < EB) {
    float4 o; o.x = rel0[tid]; o.y = rel1[tid]; o.z = rel2[tid]; o.w = cw[tid];
    relw[sslot[tid]] = o;
  }
}

// ---------------- gather: STREAMING per-node reduction (slot-ordered m_ij) ---------
__global__ __launch_bounds__(512) void gather_kernel(
    const float* __restrict__ x,
    const bf16* __restrict__ m_ij, const float4* __restrict__ relw,
    const int* __restrict__ off,
    bf16* __restrict__ m_i, float* __restrict__ xout)
{
  const int lane = threadIdx.x & 63;
  const int wv = threadIdx.x >> 6;
  const int n = blockIdx.x * 8 + wv;
  if (n >= NN) return;
  const int s = off[n];
  const int e = off[n + 1];

  float a0 = 0.f, a1 = 0.f, a2 = 0.f, a3 = 0.f;
#pragma unroll 2
  for (int j = s; j < e; ++j) {
    bf16x4 v = *(const bf16x4*)&m_ij[(long)j * HD + lane * 4];
    a0 += (float)v[0]; a1 += (float)v[1]; a2 += (float)v[2]; a3 += (float)v[3];
  }
  bf16x4 o; o[0] = (bf16)a0; o[1] = (bf16)a1; o[2] = (bf16)a2; o[3] = (bf16)a3;
  *(bf16x4*)&m_i[(long)n * HD + lane * 4] = o;

  float sx = 0.f, sy = 0.f, sz = 0.f;
  for (int j = s + lane; j < e; j += 64) {
    float4 rw = relw[j];
    sx += rw.x * rw.w; sy += rw.y * rw.w; sz += rw.z * rw.w;
  }
  for (int d = 1; d < 64; d <<= 1) {
    sx += __shfl_xor(sx, d); sy += __shfl_xor(sy, d); sz += __shfl_xor(sz, d);
  }
  if (lane == 0) {
    xout[3 * n + 0] = x[3 * n + 0] + sx;
    xout[3 * n + 1] = x[3 * n + 1] + sy;
    xout[3 * n + 2] = x[3 * n + 2] + sz;
  }
}

// ---------------- mid-tier edge kernel (R3 CSR, slot-ordered out) ------------------
__global__ __launch_bounds__(512, 4) void edge_csr_kernel(
    const float* __restrict__ h, const float* __restrict__ x,
    const int* __restrict__ ei, const int* __restrict__ eslot,
    const float* __restrict__ ea,
    const bf16* __restrict__ We1f, const float* __restrict__ be1,
    const bf16* __restrict__ We2p, const float* __restrict__ be2,
    const bf16* __restrict__ Wc1p, const float* __restrict__ bc1,
    const float* __restrict__ Wc2,
    bf16* __restrict__ m_ij, float4* __restrict__ relw)
{
  __shared__ __align__(16) bf16 ein[EB * EIN_P];
  __shared__ float rel0[EB], rel1[EB], rel2[EB];
  __shared__ float cw[EB];
  __shared__ int sidx[EB], didx[EB], sslot[EB];
  bf16* const t1s = ein;

  const int tid = threadIdx.x;
  const int e0 = blockIdx.x * EB;

  if (tid < EB) {
    int e = e0 + tid;
    int s = ei[e], d = ei[EE + e];
    sidx[tid] = s; didx[tid] = d; sslot[tid] = eslot[e];
    float rx = x[3 * s + 0] - x[3 * d + 0];
    float ry = x[3 * s + 1] - x[3 * d + 1];
    float rz = x[3 * s + 2] - x[3 * d + 2];
    rel0[tid] = rx; rel1[tid] = ry; rel2[tid] = rz;
    cw[tid] = 0.f;
  }
  __syncthreads();

  for (int i = tid; i < EB * 64; i += 512) {
    int er = i >> 6, q = i & 63;
    float4 v = ((const float4*)h)[(long)sidx[er] * 64 + q];
    bf16x4 b; b[0] = (bf16)v.x; b[1] = (bf16)v.y; b[2] = (bf16)v.z; b[3] = (bf16)v.w;
    *(bf16x4*)&ein[er * EIN_P + q * 4] = b;
  }
  for (int i = tid; i < EB * 64; i += 512) {
    int er = i >> 6, q = i & 63;
    float4 v = ((const float4*)h)[(long)didx[er] * 64 + q];
    bf16x4 b; b[0] = (bf16)v.x; b[1] = (bf16)v.y; b[2] = (bf16)v.z; b[3] = (bf16)v.w;
    *(bf16x4*)&ein[er * EIN_P + 256 + q * 4] = b;
  }
  for (int i = tid; i < EB * 16; i += 512) {
    int er = i >> 4, q = i & 15;
    float4 v = ((const float4*)ea)[(long)(e0 + er) * 16 + q];
    bf16x4 b; b[0] = (bf16)v.x; b[1] = (bf16)v.y; b[2] = (bf16)v.z; b[3] = (bf16)v.w;
    *(bf16x4*)&ein[er * EIN_P + 512 + q * 4] = b;
  }
  if (tid < EB) {
    float dsq = rel0[tid] * rel0[tid] + rel1[tid] * rel1[tid] + rel2[tid] * rel2[tid];
    ein[tid * EIN_P + 576] = (bf16)dsq;
    for (int k2 = 577; k2 < 608; ++k2) ein[tid * EIN_P + k2] = (bf16)0.f;
  }
  __syncthreads();

  const int lane = tid & 63;
  const int wv = tid >> 6;
  const int la = lane & 15, lb = lane >> 4;
  const int nc0 = wv * 2;

  f32x4 acc[4][2];

  zero_acc42(acc);
  mm64<19>(ein, EIN_P, We1f, lane, nc0, acc);
  __syncthreads();
#pragma unroll
  for (int t = 0; t < 2; ++t) {
    int col = (nc0 + t) * 16 + la;
    float bias = be1[col];
#pragma unroll
    for (int m = 0; m < 4; ++m)
#pragma unroll
      for (int r = 0; r < 4; ++r) {
        int row = m * 16 + lb * 4 + r;
        t1s[row * T1_P + col] = (bf16)silu_f(acc[m][t][r] + bias);
      }
  }
  __syncthreads();

  zero_acc42(acc);
  mm64<8>(t1s, T1_P, We2p, lane, nc0, acc);
  __syncthreads();
#pragma unroll
  for (int t = 0; t < 2; ++t) {
    int col = (nc0 + t) * 16 + la;
    float bias = be2[col];
#pragma unroll
    for (int m = 0; m < 4; ++m)
#pragma unroll
      for (int r = 0; r < 4; ++r) {
        int row = m * 16 + lb * 4 + r;
        t1s[row * T1_P + col] = (bf16)silu_f(acc[m][t][r] + bias);
      }
  }
  __syncthreads();

  for (int i = tid; i < EB * 32; i += 512) {
    int er = i >> 5, q = i & 31;
    *(bf16x8*)&m_ij[(long)sslot[er] * HD + q * 8] = *(const bf16x8*)&t1s[er * T1_P + q * 8];
  }

  zero_acc42(acc);
  mm64<8>(t1s, T1_P, Wc1p, lane, nc0, acc);
  float pr[4][4];
#pragma unroll
  for (int m = 0; m < 4; ++m)
#pragma unroll
    for (int r = 0; r < 4; ++r) pr[m][r] = 0.f;
#pragma unroll
  for (int t = 0; t < 2; ++t) {
    int col = (nc0 + t) * 16 + la;
    float bias = bc1[col];
    float wc = Wc2[col];
#pragma unroll
    for (int m = 0; m < 4; ++m)
#pragma unroll
      for (int r = 0; r < 4; ++r)
        pr[m][r] += silu_f(acc[m][t][r] + bias) * wc;
  }
#pragma unroll
  for (int m = 0; m < 4; ++m)
#pragma unroll
    for (int r = 0; r < 4; ++r) {
      float v = pr[m][r];
      v += __shfl_xor(v, 1);
      v += __shfl_xor(v, 2);
      v += __shfl_xor(v, 4);
      v += __shfl_xor(v, 8);
      if (la == 0) atomicAdd(&cw[m * 16 + lb * 4 + r], v);
    }
  __syncthreads();

  if (tid < EB) {
    float4 o; o.x = rel0[tid]; o.y = rel1[tid]; o.z = rel2[tid]; o.w = cw[tid];
    relw[sslot[tid]] = o;
  }
}

// ---------------- atomic fallback edge kernel --------------------------------------
__global__ __launch_bounds__(512, 4) void edge_atomic_kernel(
    const float* __restrict__ h, const float* __restrict__ x,
    const int* __restrict__ ei, const float* __restrict__ ea,
    const bf16* __restrict__ We1f, const float* __restrict__ be1,
    const bf16* __restrict__ We2p, const float* __restrict__ be2,
    const bf16* __restrict__ Wc1p, const float* __restrict__ bc1,
    const float* __restrict__ Wc2,
    bf16* __restrict__ m_i, float* __restrict__ xout)
{
  __shared__ __align__(16) bf16 ein[EB * EIN_P];
  __shared__ float rel0[EB], rel1[EB], rel2[EB];
  __shared__ float cw[EB];
  __shared__ int sidx[EB], didx[EB];
  bf16* const t1s = ein;

  const int tid = threadIdx.x;
  const int e0 = blockIdx.x * EB;

  if (tid < EB) {
    int e = e0 + tid;
    int s = ei[e], d = ei[EE + e];
    sidx[tid] = s; didx[tid] = d;
    float rx = x[3 * s + 0] - x[3 * d + 0];
    float ry = x[3 * s + 1] - x[3 * d + 1];
    float rz = x[3 * s + 2] - x[3 * d + 2];
    rel0[tid] = rx; rel1[tid] = ry; rel2[tid] = rz;
    cw[tid] = 0.f;
  }
  __syncthreads();
  for (int i = tid; i < EB * 64; i += 512) {
    int er = i >> 6, q = i & 63;
    float4 v = ((const float4*)h)[(long)sidx[er] * 64 + q];
    bf16x4 b; b[0] = (bf16)v.x; b[1] = (bf16)v.y; b[2] = (bf16)v.z; b[3] = (bf16)v.w;
    *(bf16x4*)&ein[er * EIN_P + q * 4] = b;
  }
  for (int i = tid; i < EB * 64; i += 512) {
    int er = i >> 6, q = i & 63;
    float4 v = ((const float4*)h)[(long)didx[er] * 64 + q];
    bf16x4 b; b[0] = (bf16)v.x; b[1] = (bf16)v.y; b[2] = (bf16)v.z; b[3] = (bf16)v.w;
    *(bf16x4*)&ein[er * EIN_P + 256 + q * 4] = b;
  }
  for (int i = tid; i < EB * 16; i += 512) {
    int er = i >> 4, q = i & 15;
    float4 v = ((const float4*)ea)[(long)(e0 + er) * 16 + q];
    bf16x4 b; b[0] = (bf16)v.x; b[1] = (bf16)v.y; b[2] = (bf16)v.z; b[3] = (bf16)v.w;
    *(bf16x4*)&ein[er * EIN_P + 512 + q * 4] = b;
  }
  if (tid < EB) {
    float dsq = rel0[tid] * rel0[tid] + rel1[tid] * rel1[tid] + rel2[tid] * rel2[tid];
    ein[tid * EIN_P + 576] = (bf16)dsq;
    for (int k2 = 577; k2 < 608; ++k2) ein[tid * EIN_P + k2] = (bf16)0.f;
  }
  __syncthreads();

  const int lane = tid & 63;
  const int wv = tid >> 6;
  const int la = lane & 15, lb = lane >> 4;
  const int rbase = (wv >> 2) * 32;
  const int nc0 = (wv & 3) * 4;

  f32x4 acc[2][4];
  zero_acc24(acc);
  mm_layer<19>(ein + rbase * EIN_P, EIN_P, We1f, lane, nc0, acc);
  __syncthreads();
#pragma unroll
  for (int t = 0; t < 4; ++t) {
    int col = (nc0 + t) * 16 + la;
    float bias = be1[col];
#pragma unroll
    for (int m = 0; m < 2; ++m)
#pragma unroll
      for (int r = 0; r < 4; ++r) {
        int row = rbase + m * 16 + lb * 4 + r;
        t1s[row * T1_P + col] = (bf16)silu_f(acc[m][t][r] + bias);
      }
  }
  __syncthreads();

  zero_acc24(acc);
  mm_layer<8>(t1s + rbase * T1_P, T1_P, We2p, lane, nc0, acc);
  int dr[2][4];
#pragma unroll
  for (int m = 0; m < 2; ++m)
#pragma unroll
    for (int r = 0; r < 4; ++r) dr[m][r] = didx[rbase + m * 16 + lb * 4 + r];
  __syncthreads();
#pragma unroll
  for (int t = 0; t < 4; ++t) {
    int col = (nc0 + t) * 16 + la;
    float bias = be2[col];
#pragma unroll
    for (int m = 0; m < 2; ++m)
#pragma unroll
      for (int r = 0; r < 4; ++r) {
        int row = rbase + m * 16 + lb * 4 + r;
        float mv = silu_f(acc[m][t][r] + bias);
        t1s[row * T1_P + col] = (bf16)mv;
        float mo = __shfl_xor(mv, 1);
        if ((la & 1) == 0)
          atomic_pk_add_bf16(&m_i[(long)dr[m][r] * HD + col], mv, mo);
      }
  }
  __syncthreads();

  zero_acc24(acc);
  mm_layer<8>(t1s + rbase * T1_P, T1_P, Wc1p, lane, nc0, acc);
  float pr[2][4];
#pragma unroll
  for (int m = 0; m < 2; ++m)
#pragma unroll
    for (int r = 0; r < 4; ++r) pr[m][r] = 0.f;
#pragma unroll
  for (int t = 0; t < 4; ++t) {
    int col = (nc0 + t) * 16 + la;
    float bias = bc1[col];
    float wc = Wc2[col];
#pragma unroll
    for (int m = 0; m < 2; ++m)
#pragma unroll
      for (int r = 0; r < 4; ++r)
        pr[m][r] += silu_f(acc[m][t][r] + bias) * wc;
  }
#pragma unroll
  for (int m = 0; m < 2; ++m)
#pragma unroll
    for (int r = 0; r < 4; ++r) {
      float v = pr[m][r];
      v += __shfl_xor(v, 1);
      v += __shfl_xor(v, 2);
      v += __shfl_xor(v, 4);
      v += __shfl_xor(v, 8);
      if (la == 0) atomicAdd(&cw[rbase + m * 16 + lb * 4 + r], v);
    }
  __syncthreads();

  if (tid < EB) {
    float wgt = cw[tid];
    int d = didx[tid];
    atomicAdd(&xout[3 * d + 0], rel0[tid] * wgt);
    atomicAdd(&xout[3 * d + 1], rel1[tid] * wgt);
    atomicAdd(&xout[3 * d + 2], rel2[tid] * wgt);
  }
}

constexpr int NB = 64;
constexpr int NIN_P = 520;

// ---------------- node kernel: h_out = h + node_mlp([h, m_i]) ----------------------
__global__ __launch_bounds__(512, 4) void node_kernel(
    const float* __restrict__ h, const bf16* __restrict__ m_i,
    const bf16* __restrict__ Wn1p, const float* __restrict__ bn1,
    const bf16* __restrict__ Wn2p, const float* __restrict__ bn2,
    float* __restrict__ hout)
{
  __shared__ __align__(16) bf16 nin[NB * NIN_P];
  bf16* const tls = nin;
  const int tid = threadIdx.x;
  const long n0 = (long)blockIdx.x * NB;

  for (int i = tid; i < NB * 64; i += 512) {
    int nr = i >> 6, q = i & 63;
    long row = n0 + nr; if (row >= NN) row = NN - 1;
    float4 v = ((const float4*)h)[row * 64 + q];
    bf16x4 b; b[0] = (bf16)v.x; b[1] = (bf16)v.y; b[2] = (bf16)v.z; b[3] = (bf16)v.w;
    *(bf16x4*)&nin[nr * NIN_P + q * 4] = b;
  }
  for (int i = tid; i < NB * 32; i += 512) {
    int nr = i >> 5, q = i & 31;
    long row = n0 + nr; if (row >= NN) row = NN - 1;
    *(bf16x8*)&nin[nr * NIN_P + 256 + q * 8] = *(const bf16x8*)&m_i[row * HD + q * 8];
  }
  __syncthreads();

  const int lane = tid & 63;
  const int wv = tid >> 6;
  const int la = lane & 15, lb = lane >> 4;
  const int rbase = (wv >> 2) * 32;
  const int nc0 = (wv & 3) * 4;

  f32x4 acc[2][4];
  zero_acc24(acc);
  mm_layer<16>(nin + rbase * NIN_P, NIN_P, Wn1p, lane, nc0, acc);
  __syncthreads();
#pragma unroll
  for (int t = 0; t < 4; ++t) {
    int col = (nc0 + t) * 16 + la;
    float bias = bn1[col];
#pragma unroll
    for (int m = 0; m < 2; ++m)
#pragma unroll
      for (int r = 0; r < 4; ++r) {
        int row = rbase + m * 16 + lb * 4 + r;
        tls[row * T1_P + col] = (bf16)silu_f(acc[m][t][r] + bias);
      }
  }
  __syncthreads();

  zero_acc24(acc);
  mm_layer<8>(tls + rbase * T1_P, T1_P, Wn2p, lane, nc0, acc);
#pragma unroll
  for (int t = 0; t < 4; ++t) {
    int col = (nc0 + t) * 16 + la;
    float bias = bn2[col];
#pragma unroll
    for (int m = 0; m < 2; ++m)
#pragma unroll
      for (int r = 0; r < 4; ++r) {
        long row = n0 + rbase + m * 16 + lb * 4 + r;
        if (row < NN)
          hout[row * HD + col] = h[row * HD + col] + acc[m][t][r] + bias;
      }
  }
}

extern "C" void kernel_launch(void* const* d_in, const int* in_sizes, int n_in,
                              void* d_out, int out_size, void* d_ws, size_t ws_size,
                              hipStream_t stream) {
  (void)in_sizes; (void)n_in; (void)out_size;
  const float* h   = (const float*)d_in[0];
  const float* x   = (const float*)d_in[1];
  const int*   ei  = (const int*)d_in[2];
  const float* ea  = (const float*)d_in[3];
  const float* We1 = (const float*)d_in[4];
  const float* be1 = (const float*)d_in[5];
  const float* We2 = (const float*)d_in[6];
  const float* be2 = (const float*)d_in[7];
  const float* Wn1 = (const float*)d_in[8];
  const float* bn1 = (const float*)d_in[9];
  const float* Wn2 = (const float*)d_in[10];
  const float* bn2 = (const float*)d_in[11];
  const float* Wc1 = (const float*)d_in[12];
  const float* bc1 = (const float*)d_in[13];
  const float* Wc2 = (const float*)d_in[14];

  float* hout = (float*)d_out;
  float* xout = hout + (long)NN * HD;
  char* ws = (char*)d_ws;

  const size_t NEED_PRE = 504278016ull;
  const size_t NEED_MID = 452898048ull;
  if (ws_size >= NEED_PRE) {
    // ---- pre-factorized path ----
    bf16*   m_ij  = (bf16*)(ws + 0);             // 409,600,000
    float4* relw  = (float4*)(ws + 409600000);   //  12,800,000
    int*    eslot = (int*)(ws + 422400000);      //   3,200,000
    int*    cnt   = (int*)(ws + 425600000);      //     200,000
    int*    offA  = (int*)(ws + 425800000);      //     200,064
    int*    cur   = (int*)(ws + 426000064);      //     200,000
    bf16*   m_i   = (bf16*)(ws + 426200064);     //  25,600,000
    bf16*   pre_s = (bf16*)(ws + 451800064);     //  25,600,000
    bf16*   pre_d = (bf16*)(ws + 477400064);     //  25,600,000
    bf16*   We1f  = (bf16*)(ws + 503000064);     //     311,296
    bf16*   We1e  = (bf16*)(ws + 503311360);     //      49,152
    bf16*   Ws1p  = (bf16*)(ws + 503360512);     //     131,072
    bf16*   Wd1p  = (bf16*)(ws + 503491584);     //     131,072
    bf16*   We2p  = (bf16*)(ws + 503622656);     //     131,072
    bf16*   Wc1p  = (bf16*)(ws + 503753728);     //     131,072
    bf16*   Wn1p  = (bf16*)(ws + 503884800);     //     262,144
    bf16*   Wn2p  = (bf16*)(ws + 504146944);     //     131,072

    prep_kernel<<<2048, 256, 0, stream>>>(x, We1, We2, Wc1, Wn1, Wn2,
                                          m_i, xout, cnt, We1f, We2p, Wc1p, Wn1p, Wn2p,
                                          Ws1p, Wd1p, We1e, 1);
    hist_kernel<<<(EE + 255) / 256, 256, 0, stream>>>(ei, cnt);
    scan_kernel<<<1, 1024, 0, stream>>>(cnt, offA, cur);
    fill_kernel<<<(EE + 255) / 256, 256, 0, stream>>>(ei, cur, eslot);
    pre_kernel<<<(NN + 63) / 64, 512, 0, stream>>>(h, Ws1p, Wd1p, pre_s, pre_d);
    edge_pre_kernel<<<EE / EB, 512, 0, stream>>>(x, ei, eslot, ea, pre_s, pre_d,
                                                 We1e, be1, We2p, be2, Wc1p, bc1, Wc2,
                                                 m_ij, relw);
    gather_kernel<<<(NN + 7) / 8, 512, 0, stream>>>(x, m_ij, relw, offA, m_i, xout);
    node_kernel<<<(NN + NB - 1) / NB, 512, 0, stream>>>(h, m_i, Wn1p, bn1, Wn2p, bn2, hout);
  } else if (ws_size >= NEED_MID) {
    // ---- R3 CSR path (slot-ordered) ----
    bf16*   m_ij  = (bf16*)(ws + 0);
    float4* relw  = (float4*)(ws + 409600000);
    int*    eslot = (int*)(ws + 422400000);
    int*    cnt   = (int*)(ws + 425600000);
    int*    offA  = (int*)(ws + 425800000);
    int*    cur   = (int*)(ws + 426000256);
    bf16*   m_i   = (bf16*)(ws + 426200320);
    bf16*   We1f  = (bf16*)(ws + 451800320);
    bf16*   We2p  = (bf16*)(ws + 452111616);
    bf16*   Wc1p  = (bf16*)(ws + 452242688);
    bf16*   Wn1p  = (bf16*)(ws + 452373760);
    bf16*   Wn2p  = (bf16*)(ws + 452635904);

    prep_kernel<<<2048, 256, 0, stream>>>(x, We1, We2, Wc1, Wn1, Wn2,
                                          m_i, xout, cnt, We1f, We2p, Wc1p, Wn1p, Wn2p,
                                          We2p, We2p, We2p, 0);
    hist_kernel<<<(EE + 255) / 256, 256, 0, stream>>>(ei, cnt);
    scan_kernel<<<1, 1024, 0, stream>>>(cnt, offA, cur);
    fill_kernel<<<(EE + 255) / 256, 256, 0, stream>>>(ei, cur, eslot);
    edge_csr_kernel<<<EE / EB, 512, 0, stream>>>(h, x, ei, eslot, ea, We1f, be1,
                                                 We2p, be2, Wc1p, bc1, Wc2, m_ij, relw);
    gather_kernel<<<(NN + 7) / 8, 512, 0, stream>>>(x, m_ij, relw, offA, m_i, xout);
    node_kernel<<<(NN + NB - 1) / NB, 512, 0, stream>>>(h, m_i, Wn1p, bn1, Wn2p, bn2, hout);
  } else {
    // ---- atomic fallback ----
    bf16* m_i  = (bf16*)ws;
    int*  cnt  = (int*)(ws + 25600000);
    bf16* We1f = (bf16*)(ws + 25800192);
    bf16* We2p = (bf16*)(ws + 26111488);
    bf16* Wc1p = (bf16*)(ws + 26242560);
    bf16* Wn1p = (bf16*)(ws + 26373632);
    bf16* Wn2p = (bf16*)(ws + 26635776);

    prep_kernel<<<2048, 256, 0, stream>>>(x, We1, We2, Wc1, Wn1, Wn2,
                                          m_i, xout, cnt, We1f, We2p, Wc1p, Wn1p, Wn2p,
                                          We2p, We2p, We2p, 0);
    edge_atomic_kernel<<<EE / EB, 512, 0, stream>>>(h, x, ei, ea, We1f, be1, We2p, be2,
                                                    Wc1p, bc1, Wc2, m_i, xout);
    node_kernel<<<(NN + NB - 1) / NB, 512, 0, stream>>>(h, m_i, Wn1p, bn1, Wn2p, bn2, hout);
  }
}

// Round 8
// 1227.435 us; speedup vs baseline: 1.5233x; 1.1743x over previous
//
#include <hip/hip_runtime.h>

#define NN 50000
#define EE 800000
#define HD 256

typedef __bf16 bf16;
typedef bf16 bf16x8 __attribute__((ext_vector_type(8)));
typedef bf16 bf16x4 __attribute__((ext_vector_type(4)));
typedef float f32x4 __attribute__((ext_vector_type(4)));

__device__ __forceinline__ float silu_f(float v) { return v / (1.f + __expf(-v)); }

// packed-weight linear index -> (k, col). Layout: [kc][nc][lane][r], r=0..7
__device__ __forceinline__ void pk_idx(int p, int& k, int& col) {
  int r = p & 7;
  int lane = (p >> 3) & 63;
  int nc = (p >> 9) & 15;
  int kc = p >> 13;
  k = kc * 32 + ((lane >> 4) << 3) + r;
  col = (nc << 4) + (lane & 15);
}

// bf16x2 packed atomic add (device scope) — atomic fallback path only.
__device__ __forceinline__ void atomic_pk_add_bf16(bf16* addr, float a, float b) {
  union { bf16 h[2]; unsigned int u; } p;
  p.h[0] = (bf16)a; p.h[1] = (bf16)b;
  asm volatile("global_atomic_pk_add_bf16 %0, %1, off"
               :: "v"((unsigned long long)(uintptr_t)addr), "v"(p.u) : "memory");
}

// ---------------- prep: zero m_i+cnt, copy x->xout, pack weights -------------------
__global__ __launch_bounds__(256) void prep_kernel(
    const float* __restrict__ x,
    const float* __restrict__ We1, const float* __restrict__ We2,
    const float* __restrict__ Wc1, const float* __restrict__ Wn1,
    const float* __restrict__ Wn2,
    bf16* __restrict__ m_i, float* __restrict__ xout, int* __restrict__ cnt,
    bf16* __restrict__ We1f, bf16* __restrict__ We2p, bf16* __restrict__ Wc1p,
    bf16* __restrict__ Wn1p, bf16* __restrict__ Wn2p,
    bf16* __restrict__ Ws1p, bf16* __restrict__ Wd1p, bf16* __restrict__ We1e,
    int pack_pre)
{
  const int stride = gridDim.x * blockDim.x;
  for (int i = blockIdx.x * blockDim.x + threadIdx.x; i < NN * HD / 2; i += stride) {
    ((unsigned int*)m_i)[i] = 0u;
    if (i < NN) cnt[i] = 0;
    if (i < 3 * NN) xout[i] = x[i];
    if (i < 19 * 8192) {  // full We1 pack (atomic/mid paths): K = hs(256) hd(256) ea(64) dsq(1) z(31)
      int k, col; pk_idx(i, k, col);
      float v = 0.f;
      if (k < 512) v = We1[k * HD + col];
      else if (k < 576) v = We1[(k + 1) * HD + col];
      else if (k == 576) v = We1[512 * HD + col];
      We1f[i] = (bf16)v;
    }
    if (i < 8 * 8192) {
      int k, col; pk_idx(i, k, col);
      We2p[i] = (bf16)We2[k * HD + col];
      Wc1p[i] = (bf16)Wc1[k * HD + col];
      Wn2p[i] = (bf16)Wn2[k * HD + col];
      if (pack_pre) {
        Ws1p[i] = (bf16)We1[k * HD + col];            // h_src rows 0..255
        Wd1p[i] = (bf16)We1[(256 + k) * HD + col];    // h_dst rows 256..511
      }
    }
    if (i < 16 * 8192) {
      int k, col; pk_idx(i, k, col);
      Wn1p[i] = (bf16)Wn1[k * HD + col];
    }
    if (pack_pre && i < 3 * 8192) {  // ea-only We1: K = ea(64) dsq(1) zeros(31)
      int k, col; pk_idx(i, k, col);
      float v = 0.f;
      if (k < 64) v = We1[(513 + k) * HD + col];
      else if (k == 64) v = We1[512 * HD + col];
      We1e[i] = (bf16)v;
    }
  }
}

// ---------------- CSR build: histogram, scan, fill (eslot) -------------------------
__global__ __launch_bounds__(256) void hist_kernel(const int* __restrict__ ei,
                                                   int* __restrict__ cnt) {
  int e = blockIdx.x * 256 + threadIdx.x;
  if (e < EE) atomicAdd(&cnt[ei[EE + e]], 1);
}

__global__ __launch_bounds__(1024) void scan_kernel(const int* __restrict__ cnt,
                                                    int* __restrict__ off,
                                                    int* __restrict__ cursor) {
  __shared__ int wsum[16];
  __shared__ int carry_s;
  const int tid = threadIdx.x, lane = tid & 63, w = tid >> 6;
  if (tid == 0) carry_s = 0;
  __syncthreads();
  for (int base = 0; base < NN; base += 1024) {
    int i = base + tid;
    int v = (i < NN) ? cnt[i] : 0;
    int sc = v;
    for (int d = 1; d < 64; d <<= 1) { int t = __shfl_up(sc, d); if (lane >= d) sc += t; }
    if (lane == 63) wsum[w] = sc;
    __syncthreads();
    if (w == 0) {
      int ws_ = (lane < 16) ? wsum[lane] : 0;
      for (int d = 1; d < 16; d <<= 1) { int t = __shfl_up(ws_, d); if (lane >= d) ws_ += t; }
      if (lane < 16) wsum[lane] = ws_;
    }
    __syncthreads();
    int woff = (w == 0) ? 0 : wsum[w - 1];
    int carry = carry_s;
    int incl = carry + woff + sc;
    if (i < NN) { off[i + 1] = incl; cursor[i] = incl - v; }
    __syncthreads();
    if (tid == 1023) carry_s = incl;
    __syncthreads();
  }
  if (threadIdx.x == 0) off[0] = 0;
}

__global__ __launch_bounds__(256) void fill_kernel(const int* __restrict__ ei,
                                                   int* __restrict__ cursor,
                                                   int* __restrict__ eslot) {
  int e = blockIdx.x * 256 + threadIdx.x;
  if (e < EE) {
    int d = ei[EE + e];
    int slot = atomicAdd(&cursor[d], 1);
    eslot[e] = slot;
  }
}

// ---------------- GEMM micro-tiles ------------------------------------------------
__device__ __forceinline__ void zero_acc24(f32x4 acc[2][4]) {
#pragma unroll
  for (int m = 0; m < 2; ++m)
#pragma unroll
    for (int t = 0; t < 4; ++t)
#pragma unroll
      for (int r = 0; r < 4; ++r) acc[m][t][r] = 0.f;
}
__device__ __forceinline__ void zero_acc42(f32x4 acc[4][2]) {
#pragma unroll
  for (int m = 0; m < 4; ++m)
#pragma unroll
    for (int t = 0; t < 2; ++t)
#pragma unroll
      for (int r = 0; r < 4; ++r) acc[m][t][r] = 0.f;
}

// 32 rows x 64 cols per wave (atomic fallback + node kernel)
template <int KC>
__device__ __forceinline__ void mm_layer(const bf16* __restrict__ Asrc, int pitch,
                                         const bf16* __restrict__ Wp, int lane, int nc0,
                                         f32x4 acc[2][4])
{
  const int la = lane & 15, lb = lane >> 4;
#pragma unroll 2
  for (int kc = 0; kc < KC; ++kc) {
    bf16x8 a0 = *(const bf16x8*)&Asrc[la * pitch + kc * 32 + lb * 8];
    bf16x8 a1 = *(const bf16x8*)&Asrc[(16 + la) * pitch + kc * 32 + lb * 8];
    const bf16x8* wp = (const bf16x8*)Wp + ((kc * 16 + nc0) * 64 + lane);
#pragma unroll
    for (int t = 0; t < 4; ++t) {
      bf16x8 b = wp[t * 64];
      acc[0][t] = __builtin_amdgcn_mfma_f32_16x16x32_bf16(a0, b, acc[0][t], 0, 0, 0);
      acc[1][t] = __builtin_amdgcn_mfma_f32_16x16x32_bf16(a1, b, acc[1][t], 0, 0, 0);
    }
  }
}

// 64 rows x 32 cols per wave: B-fragments fetched once per block
template <int KC>
__device__ __forceinline__ void mm64(const bf16* __restrict__ Asrc, int pitch,
                                     const bf16* __restrict__ Wp, int lane, int nc0,
                                     f32x4 acc[4][2])
{
  const int la = lane & 15, lb = lane >> 4;
#pragma unroll 2
  for (int kc = 0; kc < KC; ++kc) {
    bf16x8 a0 = *(const bf16x8*)&Asrc[la * pitch + kc * 32 + lb * 8];
    bf16x8 a1 = *(const bf16x8*)&Asrc[(16 + la) * pitch + kc * 32 + lb * 8];
    bf16x8 a2 = *(const bf16x8*)&Asrc[(32 + la) * pitch + kc * 32 + lb * 8];
    bf16x8 a3 = *(const bf16x8*)&Asrc[(48 + la) * pitch + kc * 32 + lb * 8];
    const bf16x8* wp = (const bf16x8*)Wp + ((kc * 16 + nc0) * 64 + lane);
#pragma unroll
    for (int t = 0; t < 2; ++t) {
      bf16x8 b = wp[t * 64];
      acc[0][t] = __builtin_amdgcn_mfma_f32_16x16x32_bf16(a0, b, acc[0][t], 0, 0, 0);
      acc[1][t] = __builtin_amdgcn_mfma_f32_16x16x32_bf16(a1, b, acc[1][t], 0, 0, 0);
      acc[2][t] = __builtin_amdgcn_mfma_f32_16x16x32_bf16(a2, b, acc[2][t], 0, 0, 0);
      acc[3][t] = __builtin_amdgcn_mfma_f32_16x16x32_bf16(a3, b, acc[3][t], 0, 0, 0);
    }
  }
}

constexpr int EB = 64;      // edges per block
constexpr int EA_P = 104;   // ea-tile pitch: 96 used, 208B = 13*16B (odd)
constexpr int EIN_P = 616;  // full-input pitch (fallback paths)
constexpr int T1_P = 264;   // 528B rows

// ---------------- pre kernel: pre_s = h@We1_top, pre_d = h@We1_mid (bf16 out) ------
__global__ __launch_bounds__(512, 4) void pre_kernel(
    const float* __restrict__ h,
    const bf16* __restrict__ Ws1p, const bf16* __restrict__ Wd1p,
    bf16* __restrict__ pre_s, bf16* __restrict__ pre_d)
{
  __shared__ __align__(16) bf16 nin[64 * T1_P];
  const int tid = threadIdx.x;
  const long n0 = (long)blockIdx.x * 64;

  for (int i = tid; i < 64 * 64; i += 512) {
    int nr = i >> 6, q = i & 63;
    long row = n0 + nr; if (row >= NN) row = NN - 1;
    float4 v = ((const float4*)h)[row * 64 + q];
    bf16x4 b; b[0] = (bf16)v.x; b[1] = (bf16)v.y; b[2] = (bf16)v.z; b[3] = (bf16)v.w;
    *(bf16x4*)&nin[nr * T1_P + q * 4] = b;
  }
  __syncthreads();

  const int lane = tid & 63;
  const int wv = tid >> 6;
  const int la = lane & 15, lb = lane >> 4;
  const int nc0 = wv * 2;

  f32x4 acc[4][2];
  zero_acc42(acc);
  mm64<8>(nin, T1_P, Ws1p, lane, nc0, acc);
#pragma unroll
  for (int t = 0; t < 2; ++t) {
    int col = (nc0 + t) * 16 + la;
#pragma unroll
    for (int m = 0; m < 4; ++m)
#pragma unroll
      for (int r = 0; r < 4; ++r) {
        long g = n0 + m * 16 + lb * 4 + r;
        if (g < NN) pre_s[g * HD + col] = (bf16)acc[m][t][r];
      }
  }
  zero_acc42(acc);
  mm64<8>(nin, T1_P, Wd1p, lane, nc0, acc);
#pragma unroll
  for (int t = 0; t < 2; ++t) {
    int col = (nc0 + t) * 16 + la;
#pragma unroll
    for (int m = 0; m < 4; ++m)
#pragma unroll
      for (int r = 0; r < 4; ++r) {
        long g = n0 + m * 16 + lb * 4 + r;
        if (g < NN) pre_d[g * HD + col] = (bf16)acc[m][t][r];
      }
  }
}

// ---------------- edge kernel: K=96 layer-1 + LDS-staged psum, slot-ordered out ----
__global__ __launch_bounds__(512, 6) void edge_pre_kernel(
    const float* __restrict__ x,
    const int* __restrict__ ei, const int* __restrict__ eslot,
    const float* __restrict__ ea,
    const bf16* __restrict__ pre_s, const bf16* __restrict__ pre_d,
    const bf16* __restrict__ We1e, const float* __restrict__ be1,
    const bf16* __restrict__ We2p, const float* __restrict__ be2,
    const bf16* __restrict__ Wc1p, const float* __restrict__ bc1,
    const float* __restrict__ Wc2,
    bf16* __restrict__ m_ij, float4* __restrict__ relw)
{
  __shared__ __align__(16) bf16 eina[EB * EA_P];  // 13.3 KB
  __shared__ __align__(16) bf16 t1s[EB * T1_P];   // 33.8 KB (psum -> t1 -> m_ij, in place)
  __shared__ float rel0[EB], rel1[EB], rel2[EB];
  __shared__ float cw[EB];
  __shared__ int sidx[EB], didx[EB], sslot[EB];

  const int tid = threadIdx.x;
  const int e0 = blockIdx.x * EB;

  if (tid < EB) {
    int e = e0 + tid;
    int s = ei[e], d = ei[EE + e];
    sidx[tid] = s; didx[tid] = d; sslot[tid] = eslot[e];
    float rx = x[3 * s + 0] - x[3 * d + 0];
    float ry = x[3 * s + 1] - x[3 * d + 1];
    float rz = x[3 * s + 2] - x[3 * d + 2];
    rel0[tid] = rx; rel1[tid] = ry; rel2[tid] = rz;
    float dsq = rx * rx + ry * ry + rz * rz;
    eina[tid * EA_P + 64] = (bf16)dsq;
#pragma unroll
    for (int k2 = 65; k2 < 96; ++k2) eina[tid * EA_P + k2] = (bf16)0.f;
    cw[tid] = 0.f;
  }
  // edge_attr gather: 2 iters/thread
  for (int i = tid; i < EB * 16; i += 512) {
    int er = i >> 4, q = i & 15;
    float4 v = ((const float4*)ea)[(long)(e0 + er) * 16 + q];
    bf16x4 b; b[0] = (bf16)v.x; b[1] = (bf16)v.y; b[2] = (bf16)v.z; b[3] = (bf16)v.w;
    *(bf16x4*)&eina[er * EA_P + q * 4] = b;
  }
  __syncthreads();  // sidx/didx valid

  // COALESCED psum staging: t1s[row] = pre_s[sidx[row]] + pre_d[didx[row]]
  // (half-wave per 512B row; 4 iters/thread of 16B loads — replaces 64 scattered
  //  2B gathers/thread in the old epilogue)
  for (int i = tid; i < EB * 32; i += 512) {
    int er = i >> 5, q = i & 31;
    bf16x8 a = *(const bf16x8*)&pre_s[(long)sidx[er] * HD + q * 8];
    bf16x8 b = *(const bf16x8*)&pre_d[(long)didx[er] * HD + q * 8];
    bf16x8 o;
#pragma unroll
    for (int k = 0; k < 8; ++k) o[k] = (bf16)((float)a[k] + (float)b[k]);
    *(bf16x8*)&t1s[er * T1_P + q * 8] = o;
  }

  const int lane = tid & 63;
  const int wv = tid >> 6;
  const int la = lane & 15, lb = lane >> 4;
  const int nc0 = wv * 2;  // 32-col slice per wave, all 64 rows

  f32x4 acc[4][2];

  // ---- layer 1: ea@We1_ea (K=96); MFMA overlaps psum staging latency ----
  zero_acc42(acc);
  mm64<3>(eina, EA_P, We1e, lane, nc0, acc);
  __syncthreads();  // all psum stores visible
#pragma unroll
  for (int t = 0; t < 2; ++t) {
    int col = (nc0 + t) * 16 + la;
    float bias = be1[col];
#pragma unroll
    for (int m = 0; m < 4; ++m)
#pragma unroll
      for (int r = 0; r < 4; ++r) {
        int row = m * 16 + lb * 4 + r;
        float v = acc[m][t][r] + bias + (float)t1s[row * T1_P + col];  // psum from LDS
        t1s[row * T1_P + col] = (bf16)silu_f(v);  // in-place: same addr, same thread
      }
  }
  __syncthreads();

  // ---- layer 2 (m_ij) ----
  zero_acc42(acc);
  mm64<8>(t1s, T1_P, We2p, lane, nc0, acc);
  __syncthreads();  // all waves done reading t1 before m_ij overlays it
#pragma unroll
  for (int t = 0; t < 2; ++t) {
    int col = (nc0 + t) * 16 + la;
    float bias = be2[col];
#pragma unroll
    for (int m = 0; m < 4; ++m)
#pragma unroll
      for (int r = 0; r < 4; ++r) {
        int row = m * 16 + lb * 4 + r;
        t1s[row * T1_P + col] = (bf16)silu_f(acc[m][t][r] + bias);
      }
  }
  __syncthreads();

  // slot-ordered m_ij scatter (coalesced 512B rows; gather will stream)
  for (int i = tid; i < EB * 32; i += 512) {
    int er = i >> 5, q = i & 31;
    *(bf16x8*)&m_ij[(long)sslot[er] * HD + q * 8] = *(const bf16x8*)&t1s[er * T1_P + q * 8];
  }

  // ---- layer 3 (coord weight); reads t1s only, concurrent with stream-out ----
  zero_acc42(acc);
  mm64<8>(t1s, T1_P, Wc1p, lane, nc0, acc);
  float pr[4][4];
#pragma unroll
  for (int m = 0; m < 4; ++m)
#pragma unroll
    for (int r = 0; r < 4; ++r) pr[m][r] = 0.f;
#pragma unroll
  for (int t = 0; t < 2; ++t) {
    int col = (nc0 + t) * 16 + la;
    float bias = bc1[col];
    float wc = Wc2[col];
#pragma unroll
    for (int m = 0; m < 4; ++m)
#pragma unroll
      for (int r = 0; r < 4; ++r)
        pr[m][r] += silu_f(acc[m][t][r] + bias) * wc;
  }
#pragma unroll
  for (int m = 0; m < 4; ++m)
#pragma unroll
    for (int r = 0; r < 4; ++r) {
      float v = pr[m][r];
      v += __shfl_xor(v, 1);
      v += __shfl_xor(v, 2);
      v += __shfl_xor(v, 4);
      v += __shfl_xor(v, 8);
      if (la == 0) atomicAdd(&cw[m * 16 + lb * 4 + r], v);  // LDS atomic
    }
  __syncthreads();

  if (tid < EB) {
    float4 o; o.x = rel0[tid]; o.y = rel1[tid]; o.z = rel2[tid]; o.w = cw[tid];
    relw[sslot[tid]] = o;
  }
}

// ---------------- gather: STREAMING per-node reduction (slot-ordered m_ij) ---------
__global__ __launch_bounds__(512) void gather_kernel(
    const float* __restrict__ x,
    const bf16* __restrict__ m_ij, const float4* __restrict__ relw,
    const int* __restrict__ off,
    bf16* __restrict__ m_i, float* __restrict__ xout)
{
  const int lane = threadIdx.x & 63;
  const int wv = threadIdx.x >> 6;
  const int n = blockIdx.x * 8 + wv;
  if (n >= NN) return;
  const int s = off[n];
  const int e = off[n + 1];

  float a0 = 0.f, a1 = 0.f, a2 = 0.f, a3 = 0.f;
#pragma unroll 2
  for (int j = s; j < e; ++j) {
    bf16x4 v = *(const bf16x4*)&m_ij[(long)j * HD + lane * 4];
    a0 += (float)v[0]; a1 += (float)v[1]; a2 += (float)v[2]; a3 += (float)v[3];
  }
  bf16x4 o; o[0] = (bf16)a0; o[1] = (bf16)a1; o[2] = (bf16)a2; o[3] = (bf16)a3;
  *(bf16x4*)&m_i[(long)n * HD + lane * 4] = o;

  float sx = 0.f, sy = 0.f, sz = 0.f;
  for (int j = s + lane; j < e; j += 64) {
    float4 rw = relw[j];
    sx += rw.x * rw.w; sy += rw.y * rw.w; sz += rw.z * rw.w;
  }
  for (int d = 1; d < 64; d <<= 1) {
    sx += __shfl_xor(sx, d); sy += __shfl_xor(sy, d); sz += __shfl_xor(sz, d);
  }
  if (lane == 0) {
    xout[3 * n + 0] = x[3 * n + 0] + sx;
    xout[3 * n + 1] = x[3 * n + 1] + sy;
    xout[3 * n + 2] = x[3 * n + 2] + sz;
  }
}

// ---------------- mid-tier edge kernel (R3 CSR, slot-ordered out) ------------------
__global__ __launch_bounds__(512, 4) void edge_csr_kernel(
    const float* __restrict__ h, const float* __restrict__ x,
    const int* __restrict__ ei, const int* __restrict__ eslot,
    const float* __restrict__ ea,
    const bf16* __restrict__ We1f, const float* __restrict__ be1,
    const bf16* __restrict__ We2p, const float* __restrict__ be2,
    const bf16* __restrict__ Wc1p, const float* __restrict__ bc1,
    const float* __restrict__ Wc2,
    bf16* __restrict__ m_ij, float4* __restrict__ relw)
{
  __shared__ __align__(16) bf16 ein[EB * EIN_P];
  __shared__ float rel0[EB], rel1[EB], rel2[EB];
  __shared__ float cw[EB];
  __shared__ int sidx[EB], didx[EB], sslot[EB];
  bf16* const t1s = ein;

  const int tid = threadIdx.x;
  const int e0 = blockIdx.x * EB;

  if (tid < EB) {
    int e = e0 + tid;
    int s = ei[e], d = ei[EE + e];
    sidx[tid] = s; didx[tid] = d; sslot[tid] = eslot[e];
    float rx = x[3 * s + 0] - x[3 * d + 0];
    float ry = x[3 * s + 1] - x[3 * d + 1];
    float rz = x[3 * s + 2] - x[3 * d + 2];
    rel0[tid] = rx; rel1[tid] = ry; rel2[tid] = rz;
    cw[tid] = 0.f;
  }
  __syncthreads();

  for (int i = tid; i < EB * 64; i += 512) {
    int er = i >> 6, q = i & 63;
    float4 v = ((const float4*)h)[(long)sidx[er] * 64 + q];
    bf16x4 b; b[0] = (bf16)v.x; b[1] = (bf16)v.y; b[2] = (bf16)v.z; b[3] = (bf16)v.w;
    *(bf16x4*)&ein[er * EIN_P + q * 4] = b;
  }
  for (int i = tid; i < EB * 64; i += 512) {
    int er = i >> 6, q = i & 63;
    float4 v = ((const float4*)h)[(long)didx[er] * 64 + q];
    bf16x4 b; b[0] = (bf16)v.x; b[1] = (bf16)v.y; b[2] = (bf16)v.z; b[3] = (bf16)v.w;
    *(bf16x4*)&ein[er * EIN_P + 256 + q * 4] = b;
  }
  for (int i = tid; i < EB * 16; i += 512) {
    int er = i >> 4, q = i & 15;
    float4 v = ((const float4*)ea)[(long)(e0 + er) * 16 + q];
    bf16x4 b; b[0] = (bf16)v.x; b[1] = (bf16)v.y; b[2] = (bf16)v.z; b[3] = (bf16)v.w;
    *(bf16x4*)&ein[er * EIN_P + 512 + q * 4] = b;
  }
  if (tid < EB) {
    float dsq = rel0[tid] * rel0[tid] + rel1[tid] * rel1[tid] + rel2[tid] * rel2[tid];
    ein[tid * EIN_P + 576] = (bf16)dsq;
    for (int k2 = 577; k2 < 608; ++k2) ein[tid * EIN_P + k2] = (bf16)0.f;
  }
  __syncthreads();

  const int lane = tid & 63;
  const int wv = tid >> 6;
  const int la = lane & 15, lb = lane >> 4;
  const int nc0 = wv * 2;

  f32x4 acc[4][2];

  zero_acc42(acc);
  mm64<19>(ein, EIN_P, We1f, lane, nc0, acc);
  __syncthreads();
#pragma unroll
  for (int t = 0; t < 2; ++t) {
    int col = (nc0 + t) * 16 + la;
    float bias = be1[col];
#pragma unroll
    for (int m = 0; m < 4; ++m)
#pragma unroll
      for (int r = 0; r < 4; ++r) {
        int row = m * 16 + lb * 4 + r;
        t1s[row * T1_P + col] = (bf16)silu_f(acc[m][t][r] + bias);
      }
  }
  __syncthreads();

  zero_acc42(acc);
  mm64<8>(t1s, T1_P, We2p, lane, nc0, acc);
  __syncthreads();
#pragma unroll
  for (int t = 0; t < 2; ++t) {
    int col = (nc0 + t) * 16 + la;
    float bias = be2[col];
#pragma unroll
    for (int m = 0; m < 4; ++m)
#pragma unroll
      for (int r = 0; r < 4; ++r) {
        int row = m * 16 + lb * 4 + r;
        t1s[row * T1_P + col] = (bf16)silu_f(acc[m][t][r] + bias);
      }
  }
  __syncthreads();

  for (int i = tid; i < EB * 32; i += 512) {
    int er = i >> 5, q = i & 31;
    *(bf16x8*)&m_ij[(long)sslot[er] * HD + q * 8] = *(const bf16x8*)&t1s[er * T1_P + q * 8];
  }

  zero_acc42(acc);
  mm64<8>(t1s, T1_P, Wc1p, lane, nc0, acc);
  float pr[4][4];
#pragma unroll
  for (int m = 0; m < 4; ++m)
#pragma unroll
    for (int r = 0; r < 4; ++r) pr[m][r] = 0.f;
#pragma unroll
  for (int t = 0; t < 2; ++t) {
    int col = (nc0 + t) * 16 + la;
    float bias = bc1[col];
    float wc = Wc2[col];
#pragma unroll
    for (int m = 0; m < 4; ++m)
#pragma unroll
      for (int r = 0; r < 4; ++r)
        pr[m][r] += silu_f(acc[m][t][r] + bias) * wc;
  }
#pragma unroll
  for (int m = 0; m < 4; ++m)
#pragma unroll
    for (int r = 0; r < 4; ++r) {
      float v = pr[m][r];
      v += __shfl_xor(v, 1);
      v += __shfl_xor(v, 2);
      v += __shfl_xor(v, 4);
      v += __shfl_xor(v, 8);
      if (la == 0) atomicAdd(&cw[m * 16 + lb * 4 + r], v);
    }
  __syncthreads();

  if (tid < EB) {
    float4 o; o.x = rel0[tid]; o.y = rel1[tid]; o.z = rel2[tid]; o.w = cw[tid];
    relw[sslot[tid]] = o;
  }
}

// ---------------- atomic fallback edge kernel --------------------------------------
__global__ __launch_bounds__(512, 4) void edge_atomic_kernel(
    const float* __restrict__ h, const float* __restrict__ x,
    const int* __restrict__ ei, const float* __restrict__ ea,
    const bf16* __restrict__ We1f, const float* __restrict__ be1,
    const bf16* __restrict__ We2p, const float* __restrict__ be2,
    const bf16* __restrict__ Wc1p, const float* __restrict__ bc1,
    const float* __restrict__ Wc2,
    bf16* __restrict__ m_i, float* __restrict__ xout)
{
  __shared__ __align__(16) bf16 ein[EB * EIN_P];
  __shared__ float rel0[EB], rel1[EB], rel2[EB];
  __shared__ float cw[EB];
  __shared__ int sidx[EB], didx[EB];
  bf16* const t1s = ein;

  const int tid = threadIdx.x;
  const int e0 = blockIdx.x * EB;

  if (tid < EB) {
    int e = e0 + tid;
    int s = ei[e], d = ei[EE + e];
    sidx[tid] = s; didx[tid] = d;
    float rx = x[3 * s + 0] - x[3 * d + 0];
    float ry = x[3 * s + 1] - x[3 * d + 1];
    float rz = x[3 * s + 2] - x[3 * d + 2];
    rel0[tid] = rx; rel1[tid] = ry; rel2[tid] = rz;
    cw[tid] = 0.f;
  }
  __syncthreads();
  for (int i = tid; i < EB * 64; i += 512) {
    int er = i >> 6, q = i & 63;
    float4 v = ((const float4*)h)[(long)sidx[er] * 64 + q];
    bf16x4 b; b[0] = (bf16)v.x; b[1] = (bf16)v.y; b[2] = (bf16)v.z; b[3] = (bf16)v.w;
    *(bf16x4*)&ein[er * EIN_P + q * 4] = b;
  }
  for (int i = tid; i < EB * 64; i += 512) {
    int er = i >> 6, q = i & 63;
    float4 v = ((const float4*)h)[(long)didx[er] * 64 + q];
    bf16x4 b; b[0] = (bf16)v.x; b[1] = (bf16)v.y; b[2] = (bf16)v.z; b[3] = (bf16)v.w;
    *(bf16x4*)&ein[er * EIN_P + 256 + q * 4] = b;
  }
  for (int i = tid; i < EB * 16; i += 512) {
    int er = i >> 4, q = i & 15;
    float4 v = ((const float4*)ea)[(long)(e0 + er) * 16 + q];
    bf16x4 b; b[0] = (bf16)v.x; b[1] = (bf16)v.y; b[2] = (bf16)v.z; b[3] = (bf16)v.w;
    *(bf16x4*)&ein[er * EIN_P + 512 + q * 4] = b;
  }
  if (tid < EB) {
    float dsq = rel0[tid] * rel0[tid] + rel1[tid] * rel1[tid] + rel2[tid] * rel2[tid];
    ein[tid * EIN_P + 576] = (bf16)dsq;
    for (int k2 = 577; k2 < 608; ++k2) ein[tid * EIN_P + k2] = (bf16)0.f;
  }
  __syncthreads();

  const int lane = tid & 63;
  const int wv = tid >> 6;
  const int la = lane & 15, lb = lane >> 4;
  const int rbase = (wv >> 2) * 32;
  const int nc0 = (wv & 3) * 4;

  f32x4 acc[2][4];
  zero_acc24(acc);
  mm_layer<19>(ein + rbase * EIN_P, EIN_P, We1f, lane, nc0, acc);
  __syncthreads();
#pragma unroll
  for (int t = 0; t < 4; ++t) {
    int col = (nc0 + t) * 16 + la;
    float bias = be1[col];
#pragma unroll
    for (int m = 0; m < 2; ++m)
#pragma unroll
      for (int r = 0; r < 4; ++r) {
        int row = rbase + m * 16 + lb * 4 + r;
        t1s[row * T1_P + col] = (bf16)silu_f(acc[m][t][r] + bias);
      }
  }
  __syncthreads();

  zero_acc24(acc);
  mm_layer<8>(t1s + rbase * T1_P, T1_P, We2p, lane, nc0, acc);
  int dr[2][4];
#pragma unroll
  for (int m = 0; m < 2; ++m)
#pragma unroll
    for (int r = 0; r < 4; ++r) dr[m][r] = didx[rbase + m * 16 + lb * 4 + r];
  __syncthreads();
#pragma unroll
  for (int t = 0; t < 4; ++t) {
    int col = (nc0 + t) * 16 + la;
    float bias = be2[col];
#pragma unroll
    for (int m = 0; m < 2; ++m)
#pragma unroll
      for (int r = 0; r < 4; ++r) {
        int row = rbase + m * 16 + lb * 4 + r;
        float mv = silu_f(acc[m][t][r] + bias);
        t1s[row * T1_P + col] = (bf16)mv;
        float mo = __shfl_xor(mv, 1);
        if ((la & 1) == 0)
          atomic_pk_add_bf16(&m_i[(long)dr[m][r] * HD + col], mv, mo);
      }
  }
  __syncthreads();

  zero_acc24(acc);
  mm_layer<8>(t1s + rbase * T1_P, T1_P, Wc1p, lane, nc0, acc);
  float pr[2][4];
#pragma unroll
  for (int m = 0; m < 2; ++m)
#pragma unroll
    for (int r = 0; r < 4; ++r) pr[m][r] = 0.f;
#pragma unroll
  for (int t = 0; t < 4; ++t) {
    int col = (nc0 + t) * 16 + la;
    float bias = bc1[col];
    float wc = Wc2[col];
#pragma unroll
    for (int m = 0; m < 2; ++m)
#pragma unroll
      for (int r = 0; r < 4; ++r)
        pr[m][r] += silu_f(acc[m][t][r] + bias) * wc;
  }
#pragma unroll
  for (int m = 0; m < 2; ++m)
#pragma unroll
    for (int r = 0; r < 4; ++r) {
      float v = pr[m][r];
      v += __shfl_xor(v, 1);
      v += __shfl_xor(v, 2);
      v += __shfl_xor(v, 4);
      v += __shfl_xor(v, 8);
      if (la == 0) atomicAdd(&cw[rbase + m * 16 + lb * 4 + r], v);
    }
  __syncthreads();

  if (tid < EB) {
    float wgt = cw[tid];
    int d = didx[tid];
    atomicAdd(&xout[3 * d + 0], rel0[tid] * wgt);
    atomicAdd(&xout[3 * d + 1], rel1[tid] * wgt);
    atomicAdd(&xout[3 * d + 2], rel2[tid] * wgt);
  }
}

constexpr int NB = 64;
constexpr int NIN_P = 520;

// ---------------- node kernel: h_out = h + node_mlp([h, m_i]) ----------------------
__global__ __launch_bounds__(512, 4) void node_kernel(
    const float* __restrict__ h, const bf16* __restrict__ m_i,
    const bf16* __restrict__ Wn1p, const float* __restrict__ bn1,
    const bf16* __restrict__ Wn2p, const float* __restrict__ bn2,
    float* __restrict__ hout)
{
  __shared__ __align__(16) bf16 nin[NB * NIN_P];
  bf16* const tls = nin;
  const int tid = threadIdx.x;
  const long n0 = (long)blockIdx.x * NB;

  for (int i = tid; i < NB * 64; i += 512) {
    int nr = i >> 6, q = i & 63;
    long row = n0 + nr; if (row >= NN) row = NN - 1;
    float4 v = ((const float4*)h)[row * 64 + q];
    bf16x4 b; b[0] = (bf16)v.x; b[1] = (bf16)v.y; b[2] = (bf16)v.z; b[3] = (bf16)v.w;
    *(bf16x4*)&nin[nr * NIN_P + q * 4] = b;
  }
  for (int i = tid; i < NB * 32; i += 512) {
    int nr = i >> 5, q = i & 31;
    long row = n0 + nr; if (row >= NN) row = NN - 1;
    *(bf16x8*)&nin[nr * NIN_P + 256 + q * 8] = *(const bf16x8*)&m_i[row * HD + q * 8];
  }
  __syncthreads();

  const int lane = tid & 63;
  const int wv = tid >> 6;
  const int la = lane & 15, lb = lane >> 4;
  const int rbase = (wv >> 2) * 32;
  const int nc0 = (wv & 3) * 4;

  f32x4 acc[2][4];
  zero_acc24(acc);
  mm_layer<16>(nin + rbase * NIN_P, NIN_P, Wn1p, lane, nc0, acc);
  __syncthreads();
#pragma unroll
  for (int t = 0; t < 4; ++t) {
    int col = (nc0 + t) * 16 + la;
    float bias = bn1[col];
#pragma unroll
    for (int m = 0; m < 2; ++m)
#pragma unroll
      for (int r = 0; r < 4; ++r) {
        int row = rbase + m * 16 + lb * 4 + r;
        tls[row * T1_P + col] = (bf16)silu_f(acc[m][t][r] + bias);
      }
  }
  __syncthreads();

  zero_acc24(acc);
  mm_layer<8>(tls + rbase * T1_P, T1_P, Wn2p, lane, nc0, acc);
#pragma unroll
  for (int t = 0; t < 4; ++t) {
    int col = (nc0 + t) * 16 + la;
    float bias = bn2[col];
#pragma unroll
    for (int m = 0; m < 2; ++m)
#pragma unroll
      for (int r = 0; r < 4; ++r) {
        long row = n0 + rbase + m * 16 + lb * 4 + r;
        if (row < NN)
          hout[row * HD + col] = h[row * HD + col] + acc[m][t][r] + bias;
      }
  }
}

extern "C" void kernel_launch(void* const* d_in, const int* in_sizes, int n_in,
                              void* d_out, int out_size, void* d_ws, size_t ws_size,
                              hipStream_t stream) {
  (void)in_sizes; (void)n_in; (void)out_size;
  const float* h   = (const float*)d_in[0];
  const float* x   = (const float*)d_in[1];
  const int*   ei  = (const int*)d_in[2];
  const float* ea  = (const float*)d_in[3];
  const float* We1 = (const float*)d_in[4];
  const float* be1 = (const float*)d_in[5];
  const float* We2 = (const float*)d_in[6];
  const float* be2 = (const float*)d_in[7];
  const float* Wn1 = (const float*)d_in[8];
  const float* bn1 = (const float*)d_in[9];
  const float* Wn2 = (const float*)d_in[10];
  const float* bn2 = (const float*)d_in[11];
  const float* Wc1 = (const float*)d_in[12];
  const float* bc1 = (const float*)d_in[13];
  const float* Wc2 = (const float*)d_in[14];

  float* hout = (float*)d_out;
  float* xout = hout + (long)NN * HD;
  char* ws = (char*)d_ws;

  const size_t NEED_PRE = 504278016ull;
  const size_t NEED_MID = 452898048ull;
  if (ws_size >= NEED_PRE) {
    // ---- pre-factorized path ----
    bf16*   m_ij  = (bf16*)(ws + 0);             // 409,600,000
    float4* relw  = (float4*)(ws + 409600000);   //  12,800,000
    int*    eslot = (int*)(ws + 422400000);      //   3,200,000
    int*    cnt   = (int*)(ws + 425600000);      //     200,000
    int*    offA  = (int*)(ws + 425800000);      //     200,064
    int*    cur   = (int*)(ws + 426000064);      //     200,000
    bf16*   m_i   = (bf16*)(ws + 426200064);     //  25,600,000
    bf16*   pre_s = (bf16*)(ws + 451800064);     //  25,600,000
    bf16*   pre_d = (bf16*)(ws + 477400064);     //  25,600,000
    bf16*   We1f  = (bf16*)(ws + 503000064);     //     311,296
    bf16*   We1e  = (bf16*)(ws + 503311360);     //      49,152
    bf16*   Ws1p  = (bf16*)(ws + 503360512);     //     131,072
    bf16*   Wd1p  = (bf16*)(ws + 503491584);     //     131,072
    bf16*   We2p  = (bf16*)(ws + 503622656);     //     131,072
    bf16*   Wc1p  = (bf16*)(ws + 503753728);     //     131,072
    bf16*   Wn1p  = (bf16*)(ws + 503884800);     //     262,144
    bf16*   Wn2p  = (bf16*)(ws + 504146944);     //     131,072

    prep_kernel<<<2048, 256, 0, stream>>>(x, We1, We2, Wc1, Wn1, Wn2,
                                          m_i, xout, cnt, We1f, We2p, Wc1p, Wn1p, Wn2p,
                                          Ws1p, Wd1p, We1e, 1);
    hist_kernel<<<(EE + 255) / 256, 256, 0, stream>>>(ei, cnt);
    scan_kernel<<<1, 1024, 0, stream>>>(cnt, offA, cur);
    fill_kernel<<<(EE + 255) / 256, 256, 0, stream>>>(ei, cur, eslot);
    pre_kernel<<<(NN + 63) / 64, 512, 0, stream>>>(h, Ws1p, Wd1p, pre_s, pre_d);
    edge_pre_kernel<<<EE / EB, 512, 0, stream>>>(x, ei, eslot, ea, pre_s, pre_d,
                                                 We1e, be1, We2p, be2, Wc1p, bc1, Wc2,
                                                 m_ij, relw);
    gather_kernel<<<(NN + 7) / 8, 512, 0, stream>>>(x, m_ij, relw, offA, m_i, xout);
    node_kernel<<<(NN + NB - 1) / NB, 512, 0, stream>>>(h, m_i, Wn1p, bn1, Wn2p, bn2, hout);
  } else if (ws_size >= NEED_MID) {
    // ---- R3 CSR path (slot-ordered) ----
    bf16*   m_ij  = (bf16*)(ws + 0);
    float4* relw  = (float4*)(ws + 409600000);
    int*    eslot = (int*)(ws + 422400000);
    int*    cnt   = (int*)(ws + 425600000);
    int*    offA  = (int*)(ws + 425800000);
    int*    cur   = (int*)(ws + 426000256);
    bf16*   m_i   = (bf16*)(ws + 426200320);
    bf16*   We1f  = (bf16*)(ws + 451800320);
    bf16*   We2p  = (bf16*)(ws + 452111616);
    bf16*   Wc1p  = (bf16*)(ws + 452242688);
    bf16*   Wn1p  = (bf16*)(ws + 452373760);
    bf16*   Wn2p  = (bf16*)(ws + 452635904);

    prep_kernel<<<2048, 256, 0, stream>>>(x, We1, We2, Wc1, Wn1, Wn2,
                                          m_i, xout, cnt, We1f, We2p, Wc1p, Wn1p, Wn2p,
                                          We2p, We2p, We2p, 0);
    hist_kernel<<<(EE + 255) / 256, 256, 0, stream>>>(ei, cnt);
    scan_kernel<<<1, 1024, 0, stream>>>(cnt, offA, cur);
    fill_kernel<<<(EE + 255) / 256, 256, 0, stream>>>(ei, cur, eslot);
    edge_csr_kernel<<<EE / EB, 512, 0, stream>>>(h, x, ei, eslot, ea, We1f, be1,
                                                 We2p, be2, Wc1p, bc1, Wc2, m_ij, relw);
    gather_kernel<<<(NN + 7) / 8, 512, 0, stream>>>(x, m_ij, relw, offA, m_i, xout);
    node_kernel<<<(NN + NB - 1) / NB, 512, 0, stream>>>(h, m_i, Wn1p, bn1, Wn2p, bn2, hout);
  } else {
    // ---- atomic fallback ----
    bf16* m_i  = (bf16*)ws;
    int*  cnt  = (int*)(ws + 25600000);
    bf16* We1f = (bf16*)(ws + 25800192);
    bf16* We2p = (bf16*)(ws + 26111488);
    bf16* Wc1p = (bf16*)(ws + 26242560);
    bf16* Wn1p = (bf16*)(ws + 26373632);
    bf16* Wn2p = (bf16*)(ws + 26635776);

    prep_kernel<<<2048, 256, 0, stream>>>(x, We1, We2, Wc1, Wn1, Wn2,
                                          m_i, xout, cnt, We1f, We2p, Wc1p, Wn1p, Wn2p,
                                          We2p, We2p, We2p, 0);
    edge_atomic_kernel<<<EE / EB, 512, 0, stream>>>(h, x, ei, ea, We1f, be1, We2p, be2,
                                                    Wc1p, bc1, Wc2, m_i, xout);
    node_kernel<<<(NN + NB - 1) / NB, 512, 0, stream>>>(h, m_i, Wn1p, bn1, Wn2p, bn2, hout);
  }
}